// Round 18
// baseline (208.523 us; speedup 1.0000x reference)
//
#include <hip/hip_runtime.h>
#include <math.h>

#define Bv 2
#define Lv 1024
#define Hv 16
#define Dv 64
#define HIDv 1024

typedef unsigned short u16;
typedef short bf16x8 __attribute__((ext_vector_type(8)));
typedef unsigned short u16x4 __attribute__((ext_vector_type(4)));
typedef float f32x4 __attribute__((ext_vector_type(4)));

// round-half-up bf16 (2 inst; exact .5-ulp ties are measure-zero)
__device__ __forceinline__ u16 f2b(float f) {
    union { float f; unsigned u; } v; v.f = f;
    return (u16)((v.u + 0x8000u) >> 16);
}
__device__ __forceinline__ float b2f(u16 h) {
    union { unsigned u; float f; } v; v.u = ((unsigned)h) << 16;
    return v.f;
}

// async global->LDS, 16B per lane (wave-uniform base + lane*16 order).
__device__ __forceinline__ void gl2lds16(const u16* g, u16* l) {
    __builtin_amdgcn_global_load_lds(
        (const __attribute__((address_space(1))) unsigned int*)g,
        (__attribute__((address_space(3))) unsigned int*)l,
        16, 0, 0);
}

// tanh-form gelu: x * sigmoid(1.5957691*(x + 0.044715*x^3)); max err ~1e-3.
__device__ __forceinline__ float gelu_fast(float x) {
    float x2 = x * x;
    float inner = __builtin_fmaf(0.044715f * x2, x, x);
    float e = __expf(-1.5957691216057308f * inner);
    return x * __builtin_amdgcn_rcpf(1.0f + e);
}

// ---------------------------------------------------------------------------
// QKV projection with fused RoPE + split + V-transpose.
// BK=64 (16 MFMA per barrier-pair) with T2 XOR-swizzle (source + read).
// LDS: As 8K + Bs 16K = 24 KB; Ct (17.4 KB) overlays. grid 24x32 = 768.
// ---------------------------------------------------------------------------
__global__ __launch_bounds__(256) void qkv_rope(
    const u16* __restrict__ A, const u16* __restrict__ B,
    const float* __restrict__ ctab, const float* __restrict__ stab,
    u16* __restrict__ q, u16* __restrict__ k, u16* __restrict__ vT)
{
    __shared__ __align__(16) char pool[24576];   // As 8KB + Bs 16KB; Ct overlay
    u16* As = (u16*)pool;                 // 64*64  u16 (8 KB), swizzled
    u16* Bs = (u16*)(pool + 8192);        // 128*64 u16 (16 KB), swizzled
    u16* Ct = (u16*)pool;                 // 64*136 u16 (epilogue only)

    const int m0 = blockIdx.y * 64;
    const int n0 = blockIdx.x * 128;
    const int K = 1024;

    const int tid = threadIdx.x;
    const int lane = tid & 63;
    const int wave = tid >> 6;
    const int wm0 = (wave >> 1) * 32;
    const int wn0 = (wave & 1) * 64;
    const int fr = lane & 15;
    const int fq = lane >> 4;

    f32x4 acc[2][4];
    #pragma unroll
    for (int i = 0; i < 2; ++i)
        #pragma unroll
        for (int j = 0; j < 4; ++j) acc[i][j] = (f32x4){0.f, 0.f, 0.f, 0.f};

    for (int k0 = 0; k0 < K; k0 += 64) {
        #pragma unroll
        for (int it = 0; it < 2; ++it) {     // A: 64 rows x 64 cols, swz source
            int cid = tid + it * 256;
            int r = cid >> 3, ch = cid & 7;
            gl2lds16(A + (long long)(m0 + r) * K + k0 + (ch ^ (r & 7)) * 8,
                     &As[cid * 8]);
        }
        #pragma unroll
        for (int it = 0; it < 4; ++it) {     // B: 128 rows x 64 cols, swz source
            int cid = tid + it * 256;
            int r = cid >> 3, ch = cid & 7;
            gl2lds16(B + (long long)(n0 + r) * K + k0 + (ch ^ (r & 7)) * 8,
                     &Bs[cid * 8]);
        }
        __syncthreads();
        bf16x8 af[2][2], bfr[4][2];
        #pragma unroll
        for (int i = 0; i < 2; ++i) {
            int row = wm0 + i * 16 + fr;
            #pragma unroll
            for (int p = 0; p < 2; ++p)
                af[i][p] = *(const bf16x8*)
                    &As[row * 64 + ((p * 32 + fq * 8) ^ ((row & 7) << 3))];
        }
        #pragma unroll
        for (int j = 0; j < 4; ++j) {
            int row = wn0 + j * 16 + fr;
            #pragma unroll
            for (int p = 0; p < 2; ++p)
                bfr[j][p] = *(const bf16x8*)
                    &Bs[row * 64 + ((p * 32 + fq * 8) ^ ((row & 7) << 3))];
        }
        #pragma unroll
        for (int p = 0; p < 2; ++p)
            #pragma unroll
            for (int i = 0; i < 2; ++i)
                #pragma unroll
                for (int j = 0; j < 4; ++j)
                    acc[i][j] = __builtin_amdgcn_mfma_f32_16x16x32_bf16(
                        af[i][p], bfr[j][p], acc[i][j], 0, 0, 0);
        __syncthreads();
    }

    const int b = m0 >> 10;                   // tile never crosses batch

    if (n0 >= 2048) {
        // ---- V: store transposed directly (4 consecutive l per lane) ----
        #pragma unroll
        for (int i = 0; i < 2; ++i)
            #pragma unroll
            for (int j = 0; j < 4; ++j) {
                int vcol = (n0 - 2048) + wn0 + j * 16 + fr;
                int head = vcol >> 6, d = vcol & 63;
                int l = ((m0 + wm0 + i * 16 + fq * 4) & 1023);
                u16 o[4];
                #pragma unroll
                for (int r = 0; r < 4; ++r) o[r] = f2b(acc[i][j][r]);
                *(u16x4*)&vT[((long long)(b * 16 + head) * 64 + d) * 1024 + l] =
                    *(u16x4*)o;
            }
        return;
    }

    // ---- Q/K: stage in LDS (overlaying As/Bs), RoPE on readback ----
    #pragma unroll
    for (int i = 0; i < 2; ++i)
        #pragma unroll
        for (int j = 0; j < 4; ++j)
            #pragma unroll
            for (int r = 0; r < 4; ++r)
                Ct[(wm0 + i * 16 + fq * 4 + r) * 136 + wn0 + j * 16 + fr] =
                    f2b(acc[i][j][r]);
    __syncthreads();

    u16* dst = (n0 >= 1024) ? k : q;
    const int nh = n0 & 1023;
    #pragma unroll
    for (int c = 0; c < 4; ++c) {
        int cid = tid + c * 256;
        int row = cid >> 4, kc = cid & 15;
        int l = (m0 + row) & 1023;
        int head = (nh >> 6) + (kc >> 3);
        int d0 = (kc & 7) * 8;
        bf16x8 x  = *(const bf16x8*)&Ct[row * 136 + kc * 8];
        bf16x8 xp = *(const bf16x8*)&Ct[row * 136 + (kc ^ 4) * 8];
        float4 c0 = *(const float4*)&ctab[l * 64 + d0];
        float4 c1 = *(const float4*)&ctab[l * 64 + d0 + 4];
        float4 s0 = *(const float4*)&stab[l * 64 + d0];
        float4 s1 = *(const float4*)&stab[l * 64 + d0 + 4];
        float ct[8] = {c0.x, c0.y, c0.z, c0.w, c1.x, c1.y, c1.z, c1.w};
        float st[8] = {s0.x, s0.y, s0.z, s0.w, s1.x, s1.y, s1.z, s1.w};
        u16 o[8];
        #pragma unroll
        for (int e = 0; e < 8; ++e)
            o[e] = f2b(b2f((u16)x[e]) * ct[e] + b2f((u16)xp[e]) * st[e]);
        *(bf16x8*)&dst[((long long)(b * 16 + head) * 1024 + l) * 64 + d0] =
            *(bf16x8*)o;
    }
}

// ---------------------------------------------------------------------------
// bf16 MFMA GEMM: C = alpha * A @ B^T. BK=64 + T2 XOR-swizzle (same proven
// transformation as qkv_rope). K-slice order preserved -> bit-identical.
// ---------------------------------------------------------------------------
template<int BM, int BN, int WM, int WN, bool CBF16>
__global__ __launch_bounds__(256) void gemm_bt(
    const u16* __restrict__ A, const u16* __restrict__ B, void* __restrict__ Cv,
    int M, int N, int K, float alpha)
{
    constexpr int NW = BN / WN;
    constexpr int MI = WM / 16;
    constexpr int NI = WN / 16;
    constexpr int LDB = BN + 8;
    constexpr int LDF = BN + 4;
    __shared__ u16 As[BM * 64];
    __shared__ u16 Bs[BN * 64];
    __shared__ u16 Ctb[CBF16 ? BM * LDB : 1];
    __shared__ float Ctf[CBF16 ? 1 : BM * LDF];

    const int m0 = blockIdx.y * BM;
    const int n0 = blockIdx.x * BN;

    const int tid = threadIdx.x;
    const int lane = tid & 63;
    const int wave = tid >> 6;
    const int wm0 = (wave / NW) * WM;
    const int wn0 = (wave % NW) * WN;
    const int fr = lane & 15;
    const int fq = lane >> 4;

    f32x4 acc[MI][NI];
    #pragma unroll
    for (int i = 0; i < MI; ++i)
        #pragma unroll
        for (int j = 0; j < NI; ++j) acc[i][j] = (f32x4){0.f, 0.f, 0.f, 0.f};

    for (int k0 = 0; k0 < K; k0 += 64) {
        #pragma unroll
        for (int it = 0; it < BM / 32; ++it) {   // BM rows x 8 chunks
            int cid = tid + it * 256;
            int r = cid >> 3, ch = cid & 7;
            gl2lds16(A + (long long)(m0 + r) * K + k0 + (ch ^ (r & 7)) * 8,
                     &As[cid * 8]);
        }
        #pragma unroll
        for (int it = 0; it < BN / 32; ++it) {
            int cid = tid + it * 256;
            int r = cid >> 3, ch = cid & 7;
            gl2lds16(B + (long long)(n0 + r) * K + k0 + (ch ^ (r & 7)) * 8,
                     &Bs[cid * 8]);
        }
        __syncthreads();
        bf16x8 af[MI][2], bfr[NI][2];
        #pragma unroll
        for (int i = 0; i < MI; ++i) {
            int row = wm0 + i * 16 + fr;
            #pragma unroll
            for (int p = 0; p < 2; ++p)
                af[i][p] = *(const bf16x8*)
                    &As[row * 64 + ((p * 32 + fq * 8) ^ ((row & 7) << 3))];
        }
        #pragma unroll
        for (int j = 0; j < NI; ++j) {
            int row = wn0 + j * 16 + fr;
            #pragma unroll
            for (int p = 0; p < 2; ++p)
                bfr[j][p] = *(const bf16x8*)
                    &Bs[row * 64 + ((p * 32 + fq * 8) ^ ((row & 7) << 3))];
        }
        #pragma unroll
        for (int p = 0; p < 2; ++p)
            #pragma unroll
            for (int i = 0; i < MI; ++i)
                #pragma unroll
                for (int j = 0; j < NI; ++j)
                    acc[i][j] = __builtin_amdgcn_mfma_f32_16x16x32_bf16(
                        af[i][p], bfr[j][p], acc[i][j], 0, 0, 0);
        __syncthreads();
    }

    #pragma unroll
    for (int i = 0; i < MI; ++i)
        #pragma unroll
        for (int j = 0; j < NI; ++j)
            #pragma unroll
            for (int r = 0; r < 4; ++r) {
                int row = wm0 + i * 16 + fq * 4 + r;
                int col = wn0 + j * 16 + fr;
                float v = acc[i][j][r] * alpha;
                if (CBF16) Ctb[row * LDB + col] = f2b(v);
                else       Ctf[row * LDF + col] = v;
            }
    __syncthreads();
    if (CBF16) {
        constexpr int CPR = BN / 8;
        #pragma unroll
        for (int c = 0; c < (BM * BN) / (8 * 256); ++c) {
            int cid = tid + c * 256;
            int row = cid / CPR, kc = cid % CPR;
            *(bf16x8*)((u16*)Cv + (long long)(m0 + row) * N + n0 + kc * 8) =
                *(const bf16x8*)&Ctb[row * LDB + kc * 8];
        }
    } else {
        constexpr int CPR = BN / 4;
        #pragma unroll
        for (int c = 0; c < (BM * BN) / (4 * 256); ++c) {
            int cid = tid + c * 256;
            int row = cid / CPR, kc = cid % CPR;
            *(float4*)((float*)Cv + (long long)(m0 + row) * N + n0 + kc * 4) =
                *(const float4*)&Ctf[row * LDF + kc * 4];
        }
    }
}

// ---------------------------------------------------------------------------
// QK^T, all 16 heads per block, scores stored TRANSPOSED: St(b, i, j, h).
// (Round-11 verified-best variant: 32i x 64j, 64 KB Ts, 2 blocks/CU.)
// Scatter into LDS (XOR-swizzled 16B halves -> 8-way), ONE barrier,
// coalesced b128 readback. grid (16, 32, B); early-exit above diagonal.
// ---------------------------------------------------------------------------
__global__ __launch_bounds__(256) void qk_allh(
    const u16* __restrict__ Q, const u16* __restrict__ K, u16* __restrict__ St)
{
    const int n0 = blockIdx.x * 64;          // j
    const int m0 = blockIdx.y * 32;          // i
    if (n0 > m0 + 31) return;                // fully above diagonal
    const int b = blockIdx.z;

    __shared__ __align__(16) u16 Ts[32 * 64 * 16];   // 65536 B

    const int tid = threadIdx.x;
    const int lane = tid & 63;
    const int wave = tid >> 6;
    const int fr = lane & 15;
    const int fq = lane >> 4;

    const long long qkbase = (long long)b * 16 * 65536;   // (b,h,l,d)
    u16* Sb = St + (long long)b * 1024 * 1024 * 16;       // (b,i,j,h)

    for (int hh = 0; hh < 4; ++hh) {
        const int h = wave * 4 + hh;
        const u16* A  = Q + qkbase + (long long)h * 65536;
        const u16* Bp = K + qkbase + (long long)h * 65536;

        bf16x8 af[2][2], bf[4][2];
        #pragma unroll
        for (int p = 0; p < 2; ++p) {
            #pragma unroll
            for (int ii = 0; ii < 2; ++ii)
                af[ii][p] = *(const bf16x8*)&A[(m0 + ii * 16 + fr) * 64 + p * 32 + fq * 8];
            #pragma unroll
            for (int j = 0; j < 4; ++j)
                bf[j][p]  = *(const bf16x8*)&Bp[(n0 + j * 16 + fr) * 64 + p * 32 + fq * 8];
        }

        f32x4 acc[2][4];
        #pragma unroll
        for (int ii = 0; ii < 2; ++ii)
            #pragma unroll
            for (int j = 0; j < 4; ++j) acc[ii][j] = (f32x4){0.f, 0.f, 0.f, 0.f};

        #pragma unroll
        for (int p = 0; p < 2; ++p)
            #pragma unroll
            for (int ii = 0; ii < 2; ++ii)
                #pragma unroll
                for (int j = 0; j < 4; ++j)
                    acc[ii][j] = __builtin_amdgcn_mfma_f32_16x16x32_bf16(
                        af[ii][p], bf[j][p], acc[ii][j], 0, 0, 0);

        // scatter this head's 32x64 tile into LDS (i, j, h), swizzled
        #pragma unroll
        for (int ii = 0; ii < 2; ++ii)
            #pragma unroll
            for (int j = 0; j < 4; ++j) {
                const int jc = j * 16 + fr;
                #pragma unroll
                for (int r = 0; r < 4; ++r) {
                    const int ir = ii * 16 + fq * 4 + r;
                    int byte = ((ir * 64 + jc) * 16 + h) * 2;
                    byte ^= (((jc + (ir >> 2)) & 1) << 4);
                    *(u16*)&((char*)Ts)[byte] = f2b(acc[ii][j][r] * 0.125f);
                }
            }
    }
    __syncthreads();

    // coalesced readback: 16 iters x 256 threads x 16B
    const long long gb = (long long)m0 * 16384 + n0 * 16;
    #pragma unroll
    for (int c = 0; c < 16; ++c) {
        int o = (c * 256 + tid) * 8;                   // elem offset in tile
        int p = ((o >> 4) + (o >> 12)) & 1;            // (jc + (ir>>2)) & 1
        int ldsb = (o * 2) ^ (p << 4);
        bf16x8 v = *(const bf16x8*)&((const char*)Ts)[ldsb];
        *(bf16x8*)&Sb[gb + (long long)(o >> 10) * 16384 + (o & 1023)] = v;
    }
}

// ---------------------------------------------------------------------------
// PV: attn_bf = W @ V^T (triangular K), gl2lds16-staged GEMM (verified
// round 17: 45us direct -> staged, total -15.9us). 256 thr, 4 waves of
// 32x32; T2 source+read swizzle. LDS 25 KB -> 6 blocks/CU.
// grid (16, B*H); writes bf16 into (B,L,H*D).
// ---------------------------------------------------------------------------
__global__ __launch_bounds__(256) void pv_direct(
    const u16* __restrict__ W, const u16* __restrict__ VT, u16* __restrict__ O)
{
    const int m0 = blockIdx.x * 64;
    const int bh = blockIdx.y;
    const u16* A = W + (long long)bh * 1048576;    // (L,L), row stride 1024
    const u16* B = VT + (long long)bh * 65536;     // (D=64,L), row stride 1024
    const int b = bh >> 4, h = bh & 15;

    __shared__ u16 As[64 * 64];    // 8 KB, swizzled W-tile
    __shared__ u16 Bs[64 * 64];    // 8 KB, swizzled V-tile
    __shared__ u16 Ct[64 * 72];    // 9 KB epilogue

    const int tid = threadIdx.x;
    const int lane = tid & 63;
    const int wave = tid >> 6;
    const int wm0 = (wave >> 1) * 32;
    const int wn0 = (wave & 1) * 32;
    const int fr = lane & 15;
    const int fq = lane >> 4;

    f32x4 acc[2][2];
    #pragma unroll
    for (int i = 0; i < 2; ++i)
        #pragma unroll
        for (int j = 0; j < 2; ++j) acc[i][j] = (f32x4){0.f, 0.f, 0.f, 0.f};

    const int Kend = m0 + 64;
    for (int k0 = 0; k0 < Kend; k0 += 64) {
        #pragma unroll
        for (int it = 0; it < 2; ++it) {     // A: 64 rows x 64 cols, swz source
            int cid = tid + it * 256;
            int r = cid >> 3, ch = cid & 7;
            gl2lds16(A + (long long)(m0 + r) * 1024 + k0 + (ch ^ (r & 7)) * 8,
                     &As[cid * 8]);
        }
        #pragma unroll
        for (int it = 0; it < 2; ++it) {     // B: 64 d-rows x 64 l-cols
            int cid = tid + it * 256;
            int r = cid >> 3, ch = cid & 7;
            gl2lds16(B + (long long)r * 1024 + k0 + (ch ^ (r & 7)) * 8,
                     &Bs[cid * 8]);
        }
        __syncthreads();
        bf16x8 af[2][2], bfr[2][2];
        #pragma unroll
        for (int i = 0; i < 2; ++i) {
            int row = wm0 + i * 16 + fr;
            #pragma unroll
            for (int p = 0; p < 2; ++p)
                af[i][p] = *(const bf16x8*)
                    &As[row * 64 + ((p * 32 + fq * 8) ^ ((row & 7) << 3))];
        }
        #pragma unroll
        for (int j = 0; j < 2; ++j) {
            int row = wn0 + j * 16 + fr;
            #pragma unroll
            for (int p = 0; p < 2; ++p)
                bfr[j][p] = *(const bf16x8*)
                    &Bs[row * 64 + ((p * 32 + fq * 8) ^ ((row & 7) << 3))];
        }
        #pragma unroll
        for (int p = 0; p < 2; ++p)
            #pragma unroll
            for (int i = 0; i < 2; ++i)
                #pragma unroll
                for (int j = 0; j < 2; ++j)
                    acc[i][j] = __builtin_amdgcn_mfma_f32_16x16x32_bf16(
                        af[i][p], bfr[j][p], acc[i][j], 0, 0, 0);
        __syncthreads();
    }

    #pragma unroll
    for (int i = 0; i < 2; ++i)
        #pragma unroll
        for (int j = 0; j < 2; ++j)
            #pragma unroll
            for (int r = 0; r < 4; ++r)
                Ct[(wm0 + i * 16 + fq * 4 + r) * 72 + wn0 + j * 16 + fr] =
                    f2b(acc[i][j][r]);
    __syncthreads();
    const long long ob = (long long)b * 1048576 + h * 64;
    #pragma unroll
    for (int c = 0; c < 2; ++c) {
        int cid = tid + c * 256;
        int row = cid >> 3, kc = cid & 7;
        *(bf16x8*)&O[ob + (long long)(m0 + row) * 1024 + kc * 8] =
            *(const bf16x8*)&Ct[row * 72 + kc * 8];
    }
}

// ---------------------------------------------------------------------------
// Fused prep: vectorized cast x (blocks 0..1023, 8 elems/thread),
// transpose wqkv (1024..1791, 768 blocks), transpose wo (1792..2047, 256
// blocks), kerple (2048..2111), rope (2112..2623). Total grid: 2624.
// ---------------------------------------------------------------------------
__global__ __launch_bounds__(256) void prep(
    const float* __restrict__ x, u16* __restrict__ x_bf,
    const float* __restrict__ w_qkv, u16* __restrict__ wqkvT,
    const float* __restrict__ w_o, u16* __restrict__ woT,
    const float* __restrict__ log_p, const float* __restrict__ log_a,
    u16* __restrict__ ktab, float* __restrict__ ctab, float* __restrict__ stab)
{
    __shared__ float tile[64][65];
    const int bid = blockIdx.x;
    const int tid = threadIdx.x;

    if (bid < 1024) {                          // x cast: 8 elems/thread
        int i8 = (bid * 256 + tid) * 8;
        float4 v0 = *(const float4*)&x[i8];
        float4 v1 = *(const float4*)&x[i8 + 4];
        u16 o[8];
        o[0] = f2b(v0.x); o[1] = f2b(v0.y); o[2] = f2b(v0.z); o[3] = f2b(v0.w);
        o[4] = f2b(v1.x); o[5] = f2b(v1.y); o[6] = f2b(v1.z); o[7] = f2b(v1.w);
        *(bf16x8*)&x_bf[i8] = *(bf16x8*)o;
        return;
    }
    if (bid >= 2112) {
        int idx = (bid - 2112) * 256 + tid;    // 0..131071: both rope tables
        int e = idx & 65535;
        int l = e >> 6, d = e & 63;
        float inv_freq = __expf((float)(d & 31) * -0.28782313662425574f);
        float arg = (float)l * inv_freq;
        if (idx < 65536) ctab[e] = __cosf(arg);
        else             stab[e] = (d < 32) ? -__sinf(arg) : __sinf(arg);
        return;
    }
    if (bid >= 2048) {
        int idx = (bid - 2048) * 256 + tid;    // 16384
        int h = idx & 15, dist = idx >> 4;
        float pp = log1pf(__expf(log_p[h]));
        float aa = log1pf(__expf(log_a[h]));
        ktab[idx] = f2b(-pp * log1pf(aa * (float)dist));
        return;
    }
    const float* src; u16* dst; int M, N, bx, by;
    if (bid < 1792) { int t = bid - 1024; bx = t % 48; by = t / 48; src = w_qkv; dst = wqkvT; M = 1024; N = 3072; }
    else            { int t = bid - 1792; bx = t % 16; by = t / 16; src = w_o;   dst = woT;   M = 1024; N = 1024; }
    const int m0 = by * 64, n0 = bx * 64;
    #pragma unroll
    for (int c = 0; c < 4; ++c) {
        int f = tid + c * 256;
        int r = f >> 4, cs = (f & 15) * 4;
        float4 v = *(const float4*)&src[(long long)(m0 + r) * N + n0 + cs];
        tile[r][cs] = v.x; tile[r][cs + 1] = v.y;
        tile[r][cs + 2] = v.z; tile[r][cs + 3] = v.w;
    }
    __syncthreads();
    int nl = tid >> 2, ms = (tid & 3) * 16;
    u16 outv[16];
    #pragma unroll
    for (int c = 0; c < 16; ++c) outv[c] = f2b(tile[ms + c][nl]);
    *(bf16x8*)&dst[(long long)(n0 + nl) * M + m0 + ms]     = *(bf16x8*)&outv[0];
    *(bf16x8*)&dst[(long long)(n0 + nl) * M + m0 + ms + 8] = *(bf16x8*)&outv[8];
}

// ---------------------------------------------------------------------------
// FUSED kerple + DAPE MLP (MFMA) + causal softmax. (MEASURED 30.5 us.)
// Reads St(b,i,j,h) DIRECTLY as MFMA fragments: lanes fq<2 read 16 head
// scores, fq>=2 read kerple; one-deep prefetch; one barrier before softmax.
// Softmax writes W(b,h,i,j) for pv_direct.
// LDS: logits 33.4 KB + per-wave hid 9.2 KB = 42.6 KB -> 3 blocks/CU.
// ---------------------------------------------------------------------------
#define LSTR 1044

__global__ __launch_bounds__(512) void dape_soft(
    const u16* __restrict__ St, u16* __restrict__ W,
    const u16* __restrict__ ktab,
    const float* __restrict__ w1, const float* __restrict__ b1,
    const float* __restrict__ w2, const float* __restrict__ b2)
{
    const int i = 1023 - blockIdx.x;
    const int b = blockIdx.y;

    __shared__ u16 logits[16 * LSTR];        // 33.4 KB
    __shared__ u16 hid[8][16 * 36];          // 9.2 KB (per-wave transpose)

    const int tid = threadIdx.x;
    const int lane = tid & 63;
    const int wave = tid >> 6;
    const int fr = lane & 15;
    const int fq = lane >> 4;

    bf16x8 B1a, B1b, B2f, Bid;
    #pragma unroll
    for (int e = 0; e < 8; ++e) {
        int c = fq * 8 + e;
        B1a[e] = (short)f2b(w1[c * 32 + fr]);
        B1b[e] = (short)f2b(w1[c * 32 + 16 + fr]);
        B2f[e] = (short)f2b(w2[c * 16 + fr]);
        Bid[e] = (short)((c == fr || c == 16 + fr) ? 0x3F80 : 0);
    }
    const float b1a = b1[fr], b1b = b1[16 + fr], b2v = b2[fr];

    const long long sti = ((long long)b * 1024 + i) * 1024;  // St row base (x16)
    const int ntile = (i >> 4) + 1;          // 16-j tiles with jt <= i
    const int slast = i >> 8;                // last live 256-segment
    u16* hidp = &hid[wave][0];

    // ---- MLP phase: per-wave autonomous, direct global fragment loads ----
    bf16x8 cur;
    {
        int t0 = (wave < ntile) ? wave : 0;
        int j = t0 * 16 + fr;
        int dist = i - j; if (dist < 0) dist = 0;
        const u16* pp = (fq < 2) ? &St[(sti + j) * 16 + fq * 8]
                                 : &ktab[dist * 16 + (fq - 2) * 8];
        cur = *(const bf16x8*)pp;
    }
    for (int t = wave; t < ntile; t += 8) {
        bf16x8 nxt = cur;
        if (t + 8 < ntile) {
            int j = (t + 8) * 16 + fr;
            int dist = i - j; if (dist < 0) dist = 0;
            const u16* pp = (fq < 2) ? &St[(sti + j) * 16 + fq * 8]
                                     : &ktab[dist * 16 + (fq - 2) * 8];
            nxt = *(const bf16x8*)pp;
        }

        f32x4 z = (f32x4){0.f, 0.f, 0.f, 0.f};
        f32x4 ac1a = __builtin_amdgcn_mfma_f32_16x16x32_bf16(cur, B1a, z, 0, 0, 0);
        f32x4 ac1b = __builtin_amdgcn_mfma_f32_16x16x32_bf16(cur, B1b, z, 0, 0, 0);
        f32x4 cres = __builtin_amdgcn_mfma_f32_16x16x32_bf16(
            cur, Bid, (f32x4){b2v, b2v, b2v, b2v}, 0, 0, 0);

        #pragma unroll
        for (int r = 0; r < 4; ++r) {
            float g0 = gelu_fast(ac1a[r] + b1a);
            float g1 = gelu_fast(ac1b[r] + b1b);
            hidp[(fq * 4 + r) * 36 + fr]      = f2b(g0);
            hidp[(fq * 4 + r) * 36 + 16 + fr] = f2b(g1);
        }
        bf16x8 A2 = *(const bf16x8*)&hidp[fr * 36 + fq * 8];
        f32x4 ac2 = __builtin_amdgcn_mfma_f32_16x16x32_bf16(A2, B2f, cres, 0, 0, 0);

        u16 o[4];
        #pragma unroll
        for (int r = 0; r < 4; ++r) o[r] = f2b(ac2[r]);
        *(u16x4*)&logits[fr * LSTR + t * 16 + fq * 4] = *(u16x4*)o;

        cur = nxt;
    }
    __syncthreads();

    // ---- wave-autonomous softmax: wave handles heads {wave, wave+8} ----
    const long long sbase = (long long)b * 16 * 1048576 + (long long)i * 1024;
    const int we = ((i >> 7) + 1) << 7;
    for (int hh = wave; hh < 16; hh += 8) {
        float vals[16];
        float mx = -3.0e38f;
        #pragma unroll
        for (int s = 0; s < 4; ++s) {
            if (s > slast) continue;                 // uniform branch
            u16x4 r4 = *(const u16x4*)&logits[hh * LSTR + lane * 4 + 256 * s];
            if (s < slast) {
                #pragma unroll
                for (int e = 0; e < 4; ++e) {
                    float v = b2f(r4[e]);
                    vals[s * 4 + e] = v;
                    mx = fmaxf(mx, v);
                }
            } else {
                #pragma unroll
                for (int e = 0; e < 4; ++e) {
                    int j = lane * 4 + 256 * s + e;
                    float v = (j <= i) ? b2f(r4[e]) : -3.0e38f;
                    vals[s * 4 + e] = v;
                    mx = fmaxf(mx, v);
                }
            }
        }
        #pragma unroll
        for (int off = 1; off < 64; off <<= 1)
            mx = fmaxf(mx, __shfl_xor(mx, off));
        float sm = 0.f;
        #pragma unroll
        for (int s = 0; s < 4; ++s) {
            if (s > slast) continue;                 // uniform branch
            if (s < slast) {
                #pragma unroll
                for (int e = 0; e < 4; ++e) {
                    float ev = __expf(vals[s * 4 + e] - mx);
                    vals[s * 4 + e] = ev;
                    sm += ev;
                }
            } else {
                #pragma unroll
                for (int e = 0; e < 4; ++e) {
                    float ev = (vals[s * 4 + e] > -1.0e37f)
                                   ? __expf(vals[s * 4 + e] - mx) : 0.f;
                    vals[s * 4 + e] = ev;
                    sm += ev;
                }
            }
        }
        #pragma unroll
        for (int off = 1; off < 64; off <<= 1)
            sm += __shfl_xor(sm, off);
        const float inv = __builtin_amdgcn_rcpf(sm);
        const long long hb = sbase + (long long)hh * 1048576;
        #pragma unroll
        for (int s = 0; s < 4; ++s) {
            if (s > slast) continue;                 // uniform branch
            int j0v = lane * 4 + 256 * s;
            if (s < slast || j0v < we) {
                u16 o[4];
                #pragma unroll
                for (int e = 0; e < 4; ++e) o[e] = f2b(vals[s * 4 + e] * inv);
                *(u16x4*)&W[hb + j0v] = *(u16x4*)o;
            }
        }
    }
}

// ---------------------------------------------------------------------------
extern "C" void kernel_launch(void* const* d_in, const int* in_sizes, int n_in,
                              void* d_out, int out_size, void* d_ws, size_t ws_size,
                              hipStream_t stream)
{
    const float* x     = (const float*)d_in[0];
    const float* w_qkv = (const float*)d_in[1];
    const float* w_o   = (const float*)d_in[2];
    const float* log_p = (const float*)d_in[3];
    const float* log_a = (const float*)d_in[4];
    const float* w1    = (const float*)d_in[5];
    const float* b1    = (const float*)d_in[6];
    const float* w2    = (const float*)d_in[7];
    const float* b2    = (const float*)d_in[8];
    float* out = (float*)d_out;

    char* p = (char*)d_ws;
    u16* x_bf    = (u16*)p;    p += 2097152ll * 2;
    u16* wqkvT   = (u16*)p;    p += 3145728ll * 2;   // (3HD, HID)
    u16* woT     = (u16*)p;    p += 1048576ll * 2;   // (HID, HD)
    u16* q_bf    = (u16*)p;    p += 2097152ll * 2;   // (B,H,L,D)
    u16* k_bf    = (u16*)p;    p += 2097152ll * 2;
    u16* vT      = (u16*)p;    p += 2097152ll * 2;   // (B,H,D,L)
    u16* scoresW = (u16*)p;    p += 33554432ll * 2;  // W: (B,H,L,L) post-softmax
    u16* St      = (u16*)p;    p += 33554432ll * 2;  // St: (B,L,L,H) raw scores
    u16* attn_bf = (u16*)p;    p += 2097152ll * 2;   // (B,L,H*D)
    u16* ktab    = (u16*)p;    p += 16384ll * 2;     // kerple[dist][h]
    float* ctab  = (float*)p;  p += 65536ll * 4;     // cos[l][d]
    float* stab  = (float*)p;  p += 65536ll * 4;     // signed sin[l][d]

    // 0. fused prep: cast x (vectorized), transpose weights, kerple + rope
    prep<<<2624, 256, 0, stream>>>(x, x_bf, w_qkv, wqkvT, w_o, woT,
                                   log_p, log_a, ktab, ctab, stab);

    // 1. qkv projection + fused RoPE/split/V-transpose (BK=64, T2 swizzle)
    qkv_rope<<<dim3(24, 32), 256, 0, stream>>>(
        x_bf, wqkvT, ctab, stab, q_bf, k_bf, vT);

    // 1b. ATTRIBUTION EXPERIMENT (round 18): qkv_rope is idempotent (reads
    // x_bf/wqkvT/tables, writes q/k/vT deterministically). Second launch
    // leaves output bit-identical; t_qkv = total - 186.4 us. This is the
    // largest unmeasured kernel (model band 25-40 us). Remove next round.
    qkv_rope<<<dim3(24, 32), 256, 0, stream>>>(
        x_bf, wqkvT, ctab, stab, q_bf, k_bf, vT);

    // 2. St = (q @ k^T)/8 for all heads, stored (b,i,j,h), LDS-staged store
    qk_allh<<<dim3(16, 32, 2), 256, 0, stream>>>(q_bf, k_bf, St);

    // 3. FUSED kerple + DAPE MLP + softmax: St -> W (measured 30.5 us)
    dape_soft<<<dim3(1024, 2), 512, 0, stream>>>(
        St, scoresW, ktab, w1, b1, w2, b2);

    // 4. attn_bf = W @ v, triangular K, gl2lds16-staged GEMM structure
    pv_direct<<<dim3(16, 32), 256, 0, stream>>>(scoresW, vT, attn_bf);

    // 5. out = attn_fl @ w_o, staged epilogue (BK=64, T2 swizzle)
    gemm_bt<64, 64, 32, 32, false><<<dim3(16, 32, 1), 256, 0, stream>>>(
        attn_bf, woT, out, 2048, 1024, 1024, 1.0f);
}

// Round 19
// 204.542 us; speedup vs baseline: 1.0195x; 1.0195x over previous
//
#include <hip/hip_runtime.h>
#include <math.h>

#define Bv 2
#define Lv 1024
#define Hv 16
#define Dv 64
#define HIDv 1024

typedef unsigned short u16;
typedef short bf16x8 __attribute__((ext_vector_type(8)));
typedef unsigned short u16x4 __attribute__((ext_vector_type(4)));
typedef float f32x4 __attribute__((ext_vector_type(4)));

// round-half-up bf16 (2 inst; exact .5-ulp ties are measure-zero)
__device__ __forceinline__ u16 f2b(float f) {
    union { float f; unsigned u; } v; v.f = f;
    return (u16)((v.u + 0x8000u) >> 16);
}
__device__ __forceinline__ float b2f(u16 h) {
    union { unsigned u; float f; } v; v.u = ((unsigned)h) << 16;
    return v.f;
}

// async global->LDS, 16B per lane (wave-uniform base + lane*16 order).
__device__ __forceinline__ void gl2lds16(const u16* g, u16* l) {
    __builtin_amdgcn_global_load_lds(
        (const __attribute__((address_space(1))) unsigned int*)g,
        (__attribute__((address_space(3))) unsigned int*)l,
        16, 0, 0);
}

// tanh-form gelu: x * sigmoid(1.5957691*(x + 0.044715*x^3)); max err ~1e-3.
__device__ __forceinline__ float gelu_fast(float x) {
    float x2 = x * x;
    float inner = __builtin_fmaf(0.044715f * x2, x, x);
    float e = __expf(-1.5957691216057308f * inner);
    return x * __builtin_amdgcn_rcpf(1.0f + e);
}

// ---------------------------------------------------------------------------
// QKV projection with fused RoPE + split + V-transpose.
// BK=64 (16 MFMA per barrier-pair) with T2 XOR-swizzle (source + read).
// MEASURED 22.1 us (round-18 double-launch).
// LDS: As 8K + Bs 16K = 24 KB; Ct (17.4 KB) overlays. grid 24x32 = 768.
// ---------------------------------------------------------------------------
__global__ __launch_bounds__(256) void qkv_rope(
    const u16* __restrict__ A, const u16* __restrict__ B,
    const float* __restrict__ ctab, const float* __restrict__ stab,
    u16* __restrict__ q, u16* __restrict__ k, u16* __restrict__ vT)
{
    __shared__ __align__(16) char pool[24576];   // As 8KB + Bs 16KB; Ct overlay
    u16* As = (u16*)pool;                 // 64*64  u16 (8 KB), swizzled
    u16* Bs = (u16*)(pool + 8192);        // 128*64 u16 (16 KB), swizzled
    u16* Ct = (u16*)pool;                 // 64*136 u16 (epilogue only)

    const int m0 = blockIdx.y * 64;
    const int n0 = blockIdx.x * 128;
    const int K = 1024;

    const int tid = threadIdx.x;
    const int lane = tid & 63;
    const int wave = tid >> 6;
    const int wm0 = (wave >> 1) * 32;
    const int wn0 = (wave & 1) * 64;
    const int fr = lane & 15;
    const int fq = lane >> 4;

    f32x4 acc[2][4];
    #pragma unroll
    for (int i = 0; i < 2; ++i)
        #pragma unroll
        for (int j = 0; j < 4; ++j) acc[i][j] = (f32x4){0.f, 0.f, 0.f, 0.f};

    for (int k0 = 0; k0 < K; k0 += 64) {
        #pragma unroll
        for (int it = 0; it < 2; ++it) {     // A: 64 rows x 64 cols, swz source
            int cid = tid + it * 256;
            int r = cid >> 3, ch = cid & 7;
            gl2lds16(A + (long long)(m0 + r) * K + k0 + (ch ^ (r & 7)) * 8,
                     &As[cid * 8]);
        }
        #pragma unroll
        for (int it = 0; it < 4; ++it) {     // B: 128 rows x 64 cols, swz source
            int cid = tid + it * 256;
            int r = cid >> 3, ch = cid & 7;
            gl2lds16(B + (long long)(n0 + r) * K + k0 + (ch ^ (r & 7)) * 8,
                     &Bs[cid * 8]);
        }
        __syncthreads();
        bf16x8 af[2][2], bfr[4][2];
        #pragma unroll
        for (int i = 0; i < 2; ++i) {
            int row = wm0 + i * 16 + fr;
            #pragma unroll
            for (int p = 0; p < 2; ++p)
                af[i][p] = *(const bf16x8*)
                    &As[row * 64 + ((p * 32 + fq * 8) ^ ((row & 7) << 3))];
        }
        #pragma unroll
        for (int j = 0; j < 4; ++j) {
            int row = wn0 + j * 16 + fr;
            #pragma unroll
            for (int p = 0; p < 2; ++p)
                bfr[j][p] = *(const bf16x8*)
                    &Bs[row * 64 + ((p * 32 + fq * 8) ^ ((row & 7) << 3))];
        }
        #pragma unroll
        for (int p = 0; p < 2; ++p)
            #pragma unroll
            for (int i = 0; i < 2; ++i)
                #pragma unroll
                for (int j = 0; j < 4; ++j)
                    acc[i][j] = __builtin_amdgcn_mfma_f32_16x16x32_bf16(
                        af[i][p], bfr[j][p], acc[i][j], 0, 0, 0);
        __syncthreads();
    }

    const int b = m0 >> 10;                   // tile never crosses batch

    if (n0 >= 2048) {
        // ---- V: store transposed directly (4 consecutive l per lane) ----
        #pragma unroll
        for (int i = 0; i < 2; ++i)
            #pragma unroll
            for (int j = 0; j < 4; ++j) {
                int vcol = (n0 - 2048) + wn0 + j * 16 + fr;
                int head = vcol >> 6, d = vcol & 63;
                int l = ((m0 + wm0 + i * 16 + fq * 4) & 1023);
                u16 o[4];
                #pragma unroll
                for (int r = 0; r < 4; ++r) o[r] = f2b(acc[i][j][r]);
                *(u16x4*)&vT[((long long)(b * 16 + head) * 64 + d) * 1024 + l] =
                    *(u16x4*)o;
            }
        return;
    }

    // ---- Q/K: stage in LDS (overlaying As/Bs), RoPE on readback ----
    #pragma unroll
    for (int i = 0; i < 2; ++i)
        #pragma unroll
        for (int j = 0; j < 4; ++j)
            #pragma unroll
            for (int r = 0; r < 4; ++r)
                Ct[(wm0 + i * 16 + fq * 4 + r) * 136 + wn0 + j * 16 + fr] =
                    f2b(acc[i][j][r]);
    __syncthreads();

    u16* dst = (n0 >= 1024) ? k : q;
    const int nh = n0 & 1023;
    #pragma unroll
    for (int c = 0; c < 4; ++c) {
        int cid = tid + c * 256;
        int row = cid >> 4, kc = cid & 15;
        int l = (m0 + row) & 1023;
        int head = (nh >> 6) + (kc >> 3);
        int d0 = (kc & 7) * 8;
        bf16x8 x  = *(const bf16x8*)&Ct[row * 136 + kc * 8];
        bf16x8 xp = *(const bf16x8*)&Ct[row * 136 + (kc ^ 4) * 8];
        float4 c0 = *(const float4*)&ctab[l * 64 + d0];
        float4 c1 = *(const float4*)&ctab[l * 64 + d0 + 4];
        float4 s0 = *(const float4*)&stab[l * 64 + d0];
        float4 s1 = *(const float4*)&stab[l * 64 + d0 + 4];
        float ct[8] = {c0.x, c0.y, c0.z, c0.w, c1.x, c1.y, c1.z, c1.w};
        float st[8] = {s0.x, s0.y, s0.z, s0.w, s1.x, s1.y, s1.z, s1.w};
        u16 o[8];
        #pragma unroll
        for (int e = 0; e < 8; ++e)
            o[e] = f2b(b2f((u16)x[e]) * ct[e] + b2f((u16)xp[e]) * st[e]);
        *(bf16x8*)&dst[((long long)(b * 16 + head) * 1024 + l) * 64 + d0] =
            *(bf16x8*)o;
    }
}

// ---------------------------------------------------------------------------
// bf16 MFMA GEMM: C = alpha * A @ B^T. BK=64 + T2 XOR-swizzle (same proven
// transformation as qkv_rope). K-slice order preserved -> bit-identical.
// ---------------------------------------------------------------------------
template<int BM, int BN, int WM, int WN, bool CBF16>
__global__ __launch_bounds__(256) void gemm_bt(
    const u16* __restrict__ A, const u16* __restrict__ B, void* __restrict__ Cv,
    int M, int N, int K, float alpha)
{
    constexpr int NW = BN / WN;
    constexpr int MI = WM / 16;
    constexpr int NI = WN / 16;
    constexpr int LDB = BN + 8;
    constexpr int LDF = BN + 4;
    __shared__ u16 As[BM * 64];
    __shared__ u16 Bs[BN * 64];
    __shared__ u16 Ctb[CBF16 ? BM * LDB : 1];
    __shared__ float Ctf[CBF16 ? 1 : BM * LDF];

    const int m0 = blockIdx.y * BM;
    const int n0 = blockIdx.x * BN;

    const int tid = threadIdx.x;
    const int lane = tid & 63;
    const int wave = tid >> 6;
    const int wm0 = (wave / NW) * WM;
    const int wn0 = (wave % NW) * WN;
    const int fr = lane & 15;
    const int fq = lane >> 4;

    f32x4 acc[MI][NI];
    #pragma unroll
    for (int i = 0; i < MI; ++i)
        #pragma unroll
        for (int j = 0; j < NI; ++j) acc[i][j] = (f32x4){0.f, 0.f, 0.f, 0.f};

    for (int k0 = 0; k0 < K; k0 += 64) {
        #pragma unroll
        for (int it = 0; it < BM / 32; ++it) {   // BM rows x 8 chunks
            int cid = tid + it * 256;
            int r = cid >> 3, ch = cid & 7;
            gl2lds16(A + (long long)(m0 + r) * K + k0 + (ch ^ (r & 7)) * 8,
                     &As[cid * 8]);
        }
        #pragma unroll
        for (int it = 0; it < BN / 32; ++it) {
            int cid = tid + it * 256;
            int r = cid >> 3, ch = cid & 7;
            gl2lds16(B + (long long)(n0 + r) * K + k0 + (ch ^ (r & 7)) * 8,
                     &Bs[cid * 8]);
        }
        __syncthreads();
        bf16x8 af[MI][2], bfr[NI][2];
        #pragma unroll
        for (int i = 0; i < MI; ++i) {
            int row = wm0 + i * 16 + fr;
            #pragma unroll
            for (int p = 0; p < 2; ++p)
                af[i][p] = *(const bf16x8*)
                    &As[row * 64 + ((p * 32 + fq * 8) ^ ((row & 7) << 3))];
        }
        #pragma unroll
        for (int j = 0; j < NI; ++j) {
            int row = wn0 + j * 16 + fr;
            #pragma unroll
            for (int p = 0; p < 2; ++p)
                bfr[j][p] = *(const bf16x8*)
                    &Bs[row * 64 + ((p * 32 + fq * 8) ^ ((row & 7) << 3))];
        }
        #pragma unroll
        for (int p = 0; p < 2; ++p)
            #pragma unroll
            for (int i = 0; i < MI; ++i)
                #pragma unroll
                for (int j = 0; j < NI; ++j)
                    acc[i][j] = __builtin_amdgcn_mfma_f32_16x16x32_bf16(
                        af[i][p], bfr[j][p], acc[i][j], 0, 0, 0);
        __syncthreads();
    }

    #pragma unroll
    for (int i = 0; i < MI; ++i)
        #pragma unroll
        for (int j = 0; j < NI; ++j)
            #pragma unroll
            for (int r = 0; r < 4; ++r) {
                int row = wm0 + i * 16 + fq * 4 + r;
                int col = wn0 + j * 16 + fr;
                float v = acc[i][j][r] * alpha;
                if (CBF16) Ctb[row * LDB + col] = f2b(v);
                else       Ctf[row * LDF + col] = v;
            }
    __syncthreads();
    if (CBF16) {
        constexpr int CPR = BN / 8;
        #pragma unroll
        for (int c = 0; c < (BM * BN) / (8 * 256); ++c) {
            int cid = tid + c * 256;
            int row = cid / CPR, kc = cid % CPR;
            *(bf16x8*)((u16*)Cv + (long long)(m0 + row) * N + n0 + kc * 8) =
                *(const bf16x8*)&Ctb[row * LDB + kc * 8];
        }
    } else {
        constexpr int CPR = BN / 4;
        #pragma unroll
        for (int c = 0; c < (BM * BN) / (4 * 256); ++c) {
            int cid = tid + c * 256;
            int row = cid / CPR, kc = cid % CPR;
            *(float4*)((float*)Cv + (long long)(m0 + row) * N + n0 + kc * 4) =
                *(const float4*)&Ctf[row * LDF + kc * 4];
        }
    }
}

// ---------------------------------------------------------------------------
// QK^T, all 16 heads per block, scores stored TRANSPOSED: St(b, i, j, h).
// (Round-11 verified-best variant: 32i x 64j, 64 KB Ts, 2 blocks/CU.)
// Scatter into LDS (XOR-swizzled 16B halves -> 8-way), ONE barrier,
// coalesced b128 readback. grid (16, 32, B); early-exit above diagonal.
// ---------------------------------------------------------------------------
__global__ __launch_bounds__(256) void qk_allh(
    const u16* __restrict__ Q, const u16* __restrict__ K, u16* __restrict__ St)
{
    const int n0 = blockIdx.x * 64;          // j
    const int m0 = blockIdx.y * 32;          // i
    if (n0 > m0 + 31) return;                // fully above diagonal
    const int b = blockIdx.z;

    __shared__ __align__(16) u16 Ts[32 * 64 * 16];   // 65536 B

    const int tid = threadIdx.x;
    const int lane = tid & 63;
    const int wave = tid >> 6;
    const int fr = lane & 15;
    const int fq = lane >> 4;

    const long long qkbase = (long long)b * 16 * 65536;   // (b,h,l,d)
    u16* Sb = St + (long long)b * 1024 * 1024 * 16;       // (b,i,j,h)

    for (int hh = 0; hh < 4; ++hh) {
        const int h = wave * 4 + hh;
        const u16* A  = Q + qkbase + (long long)h * 65536;
        const u16* Bp = K + qkbase + (long long)h * 65536;

        bf16x8 af[2][2], bf[4][2];
        #pragma unroll
        for (int p = 0; p < 2; ++p) {
            #pragma unroll
            for (int ii = 0; ii < 2; ++ii)
                af[ii][p] = *(const bf16x8*)&A[(m0 + ii * 16 + fr) * 64 + p * 32 + fq * 8];
            #pragma unroll
            for (int j = 0; j < 4; ++j)
                bf[j][p]  = *(const bf16x8*)&Bp[(n0 + j * 16 + fr) * 64 + p * 32 + fq * 8];
        }

        f32x4 acc[2][4];
        #pragma unroll
        for (int ii = 0; ii < 2; ++ii)
            #pragma unroll
            for (int j = 0; j < 4; ++j) acc[ii][j] = (f32x4){0.f, 0.f, 0.f, 0.f};

        #pragma unroll
        for (int p = 0; p < 2; ++p)
            #pragma unroll
            for (int ii = 0; ii < 2; ++ii)
                #pragma unroll
                for (int j = 0; j < 4; ++j)
                    acc[ii][j] = __builtin_amdgcn_mfma_f32_16x16x32_bf16(
                        af[ii][p], bf[j][p], acc[ii][j], 0, 0, 0);

        // scatter this head's 32x64 tile into LDS (i, j, h), swizzled
        #pragma unroll
        for (int ii = 0; ii < 2; ++ii)
            #pragma unroll
            for (int j = 0; j < 4; ++j) {
                const int jc = j * 16 + fr;
                #pragma unroll
                for (int r = 0; r < 4; ++r) {
                    const int ir = ii * 16 + fq * 4 + r;
                    int byte = ((ir * 64 + jc) * 16 + h) * 2;
                    byte ^= (((jc + (ir >> 2)) & 1) << 4);
                    *(u16*)&((char*)Ts)[byte] = f2b(acc[ii][j][r] * 0.125f);
                }
            }
    }
    __syncthreads();

    // coalesced readback: 16 iters x 256 threads x 16B
    const long long gb = (long long)m0 * 16384 + n0 * 16;
    #pragma unroll
    for (int c = 0; c < 16; ++c) {
        int o = (c * 256 + tid) * 8;                   // elem offset in tile
        int p = ((o >> 4) + (o >> 12)) & 1;            // (jc + (ir>>2)) & 1
        int ldsb = (o * 2) ^ (p << 4);
        bf16x8 v = *(const bf16x8*)&((const char*)Ts)[ldsb];
        *(bf16x8*)&Sb[gb + (long long)(o >> 10) * 16384 + (o & 1023)] = v;
    }
}

// ---------------------------------------------------------------------------
// PV: attn_bf = W @ V^T (triangular K), gl2lds16-staged GEMM (verified
// round 17: 45us direct -> staged, total -15.9us). 256 thr, 4 waves of
// 32x32; T2 source+read swizzle. LDS 25 KB -> 6 blocks/CU.
// grid (16, B*H); writes bf16 into (B,L,H*D).
// ---------------------------------------------------------------------------
__global__ __launch_bounds__(256) void pv_direct(
    const u16* __restrict__ W, const u16* __restrict__ VT, u16* __restrict__ O)
{
    const int m0 = blockIdx.x * 64;
    const int bh = blockIdx.y;
    const u16* A = W + (long long)bh * 1048576;    // (L,L), row stride 1024
    const u16* B = VT + (long long)bh * 65536;     // (D=64,L), row stride 1024
    const int b = bh >> 4, h = bh & 15;

    __shared__ u16 As[64 * 64];    // 8 KB, swizzled W-tile
    __shared__ u16 Bs[64 * 64];    // 8 KB, swizzled V-tile
    __shared__ u16 Ct[64 * 72];    // 9 KB epilogue

    const int tid = threadIdx.x;
    const int lane = tid & 63;
    const int wave = tid >> 6;
    const int wm0 = (wave >> 1) * 32;
    const int wn0 = (wave & 1) * 32;
    const int fr = lane & 15;
    const int fq = lane >> 4;

    f32x4 acc[2][2];
    #pragma unroll
    for (int i = 0; i < 2; ++i)
        #pragma unroll
        for (int j = 0; j < 2; ++j) acc[i][j] = (f32x4){0.f, 0.f, 0.f, 0.f};

    const int Kend = m0 + 64;
    for (int k0 = 0; k0 < Kend; k0 += 64) {
        #pragma unroll
        for (int it = 0; it < 2; ++it) {     // A: 64 rows x 64 cols, swz source
            int cid = tid + it * 256;
            int r = cid >> 3, ch = cid & 7;
            gl2lds16(A + (long long)(m0 + r) * 1024 + k0 + (ch ^ (r & 7)) * 8,
                     &As[cid * 8]);
        }
        #pragma unroll
        for (int it = 0; it < 2; ++it) {     // B: 64 d-rows x 64 l-cols
            int cid = tid + it * 256;
            int r = cid >> 3, ch = cid & 7;
            gl2lds16(B + (long long)r * 1024 + k0 + (ch ^ (r & 7)) * 8,
                     &Bs[cid * 8]);
        }
        __syncthreads();
        bf16x8 af[2][2], bfr[2][2];
        #pragma unroll
        for (int i = 0; i < 2; ++i) {
            int row = wm0 + i * 16 + fr;
            #pragma unroll
            for (int p = 0; p < 2; ++p)
                af[i][p] = *(const bf16x8*)
                    &As[row * 64 + ((p * 32 + fq * 8) ^ ((row & 7) << 3))];
        }
        #pragma unroll
        for (int j = 0; j < 2; ++j) {
            int row = wn0 + j * 16 + fr;
            #pragma unroll
            for (int p = 0; p < 2; ++p)
                bfr[j][p] = *(const bf16x8*)
                    &Bs[row * 64 + ((p * 32 + fq * 8) ^ ((row & 7) << 3))];
        }
        #pragma unroll
        for (int p = 0; p < 2; ++p)
            #pragma unroll
            for (int i = 0; i < 2; ++i)
                #pragma unroll
                for (int j = 0; j < 2; ++j)
                    acc[i][j] = __builtin_amdgcn_mfma_f32_16x16x32_bf16(
                        af[i][p], bfr[j][p], acc[i][j], 0, 0, 0);
        __syncthreads();
    }

    #pragma unroll
    for (int i = 0; i < 2; ++i)
        #pragma unroll
        for (int j = 0; j < 2; ++j)
            #pragma unroll
            for (int r = 0; r < 4; ++r)
                Ct[(wm0 + i * 16 + fq * 4 + r) * 72 + wn0 + j * 16 + fr] =
                    f2b(acc[i][j][r]);
    __syncthreads();
    const long long ob = (long long)b * 1048576 + h * 64;
    #pragma unroll
    for (int c = 0; c < 2; ++c) {
        int cid = tid + c * 256;
        int row = cid >> 3, kc = cid & 7;
        *(bf16x8*)&O[ob + (long long)(m0 + row) * 1024 + kc * 8] =
            *(const bf16x8*)&Ct[row * 72 + kc * 8];
    }
}

// ---------------------------------------------------------------------------
// Fused prep: vectorized cast x (blocks 0..1023, 8 elems/thread),
// transpose wqkv (1024..1791, 768 blocks), transpose wo (1792..2047, 256
// blocks), kerple (2048..2111), rope (2112..2623). Total grid: 2624.
// ---------------------------------------------------------------------------
__global__ __launch_bounds__(256) void prep(
    const float* __restrict__ x, u16* __restrict__ x_bf,
    const float* __restrict__ w_qkv, u16* __restrict__ wqkvT,
    const float* __restrict__ w_o, u16* __restrict__ woT,
    const float* __restrict__ log_p, const float* __restrict__ log_a,
    u16* __restrict__ ktab, float* __restrict__ ctab, float* __restrict__ stab)
{
    __shared__ float tile[64][65];
    const int bid = blockIdx.x;
    const int tid = threadIdx.x;

    if (bid < 1024) {                          // x cast: 8 elems/thread
        int i8 = (bid * 256 + tid) * 8;
        float4 v0 = *(const float4*)&x[i8];
        float4 v1 = *(const float4*)&x[i8 + 4];
        u16 o[8];
        o[0] = f2b(v0.x); o[1] = f2b(v0.y); o[2] = f2b(v0.z); o[3] = f2b(v0.w);
        o[4] = f2b(v1.x); o[5] = f2b(v1.y); o[6] = f2b(v1.z); o[7] = f2b(v1.w);
        *(bf16x8*)&x_bf[i8] = *(bf16x8*)o;
        return;
    }
    if (bid >= 2112) {
        int idx = (bid - 2112) * 256 + tid;    // 0..131071: both rope tables
        int e = idx & 65535;
        int l = e >> 6, d = e & 63;
        float inv_freq = __expf((float)(d & 31) * -0.28782313662425574f);
        float arg = (float)l * inv_freq;
        if (idx < 65536) ctab[e] = __cosf(arg);
        else             stab[e] = (d < 32) ? -__sinf(arg) : __sinf(arg);
        return;
    }
    if (bid >= 2048) {
        int idx = (bid - 2048) * 256 + tid;    // 16384
        int h = idx & 15, dist = idx >> 4;
        float pp = log1pf(__expf(log_p[h]));
        float aa = log1pf(__expf(log_a[h]));
        ktab[idx] = f2b(-pp * log1pf(aa * (float)dist));
        return;
    }
    const float* src; u16* dst; int M, N, bx, by;
    if (bid < 1792) { int t = bid - 1024; bx = t % 48; by = t / 48; src = w_qkv; dst = wqkvT; M = 1024; N = 3072; }
    else            { int t = bid - 1792; bx = t % 16; by = t / 16; src = w_o;   dst = woT;   M = 1024; N = 1024; }
    const int m0 = by * 64, n0 = bx * 64;
    #pragma unroll
    for (int c = 0; c < 4; ++c) {
        int f = tid + c * 256;
        int r = f >> 4, cs = (f & 15) * 4;
        float4 v = *(const float4*)&src[(long long)(m0 + r) * N + n0 + cs];
        tile[r][cs] = v.x; tile[r][cs + 1] = v.y;
        tile[r][cs + 2] = v.z; tile[r][cs + 3] = v.w;
    }
    __syncthreads();
    int nl = tid >> 2, ms = (tid & 3) * 16;
    u16 outv[16];
    #pragma unroll
    for (int c = 0; c < 16; ++c) outv[c] = f2b(tile[ms + c][nl]);
    *(bf16x8*)&dst[(long long)(n0 + nl) * M + m0 + ms]     = *(bf16x8*)&outv[0];
    *(bf16x8*)&dst[(long long)(n0 + nl) * M + m0 + ms + 8] = *(bf16x8*)&outv[8];
}

// ---------------------------------------------------------------------------
// FUSED kerple + DAPE MLP (MFMA) + causal softmax. (MEASURED 30.5 us.)
// Reads St(b,i,j,h) DIRECTLY as MFMA fragments: lanes fq<2 read 16 head
// scores, fq>=2 read kerple; one-deep prefetch; one barrier before softmax.
// Softmax writes W(b,h,i,j) for pv_direct.
// LDS: logits 33.4 KB + per-wave hid 9.2 KB = 42.6 KB -> 3 blocks/CU.
// ---------------------------------------------------------------------------
#define LSTR 1044

__global__ __launch_bounds__(512) void dape_soft(
    const u16* __restrict__ St, u16* __restrict__ W,
    const u16* __restrict__ ktab,
    const float* __restrict__ w1, const float* __restrict__ b1,
    const float* __restrict__ w2, const float* __restrict__ b2)
{
    const int i = 1023 - blockIdx.x;
    const int b = blockIdx.y;

    __shared__ u16 logits[16 * LSTR];        // 33.4 KB
    __shared__ u16 hid[8][16 * 36];          // 9.2 KB (per-wave transpose)

    const int tid = threadIdx.x;
    const int lane = tid & 63;
    const int wave = tid >> 6;
    const int fr = lane & 15;
    const int fq = lane >> 4;

    bf16x8 B1a, B1b, B2f, Bid;
    #pragma unroll
    for (int e = 0; e < 8; ++e) {
        int c = fq * 8 + e;
        B1a[e] = (short)f2b(w1[c * 32 + fr]);
        B1b[e] = (short)f2b(w1[c * 32 + 16 + fr]);
        B2f[e] = (short)f2b(w2[c * 16 + fr]);
        Bid[e] = (short)((c == fr || c == 16 + fr) ? 0x3F80 : 0);
    }
    const float b1a = b1[fr], b1b = b1[16 + fr], b2v = b2[fr];

    const long long sti = ((long long)b * 1024 + i) * 1024;  // St row base (x16)
    const int ntile = (i >> 4) + 1;          // 16-j tiles with jt <= i
    const int slast = i >> 8;                // last live 256-segment
    u16* hidp = &hid[wave][0];

    // ---- MLP phase: per-wave autonomous, direct global fragment loads ----
    bf16x8 cur;
    {
        int t0 = (wave < ntile) ? wave : 0;
        int j = t0 * 16 + fr;
        int dist = i - j; if (dist < 0) dist = 0;
        const u16* pp = (fq < 2) ? &St[(sti + j) * 16 + fq * 8]
                                 : &ktab[dist * 16 + (fq - 2) * 8];
        cur = *(const bf16x8*)pp;
    }
    for (int t = wave; t < ntile; t += 8) {
        bf16x8 nxt = cur;
        if (t + 8 < ntile) {
            int j = (t + 8) * 16 + fr;
            int dist = i - j; if (dist < 0) dist = 0;
            const u16* pp = (fq < 2) ? &St[(sti + j) * 16 + fq * 8]
                                     : &ktab[dist * 16 + (fq - 2) * 8];
            nxt = *(const bf16x8*)pp;
        }

        f32x4 z = (f32x4){0.f, 0.f, 0.f, 0.f};
        f32x4 ac1a = __builtin_amdgcn_mfma_f32_16x16x32_bf16(cur, B1a, z, 0, 0, 0);
        f32x4 ac1b = __builtin_amdgcn_mfma_f32_16x16x32_bf16(cur, B1b, z, 0, 0, 0);
        f32x4 cres = __builtin_amdgcn_mfma_f32_16x16x32_bf16(
            cur, Bid, (f32x4){b2v, b2v, b2v, b2v}, 0, 0, 0);

        #pragma unroll
        for (int r = 0; r < 4; ++r) {
            float g0 = gelu_fast(ac1a[r] + b1a);
            float g1 = gelu_fast(ac1b[r] + b1b);
            hidp[(fq * 4 + r) * 36 + fr]      = f2b(g0);
            hidp[(fq * 4 + r) * 36 + 16 + fr] = f2b(g1);
        }
        bf16x8 A2 = *(const bf16x8*)&hidp[fr * 36 + fq * 8];
        f32x4 ac2 = __builtin_amdgcn_mfma_f32_16x16x32_bf16(A2, B2f, cres, 0, 0, 0);

        u16 o[4];
        #pragma unroll
        for (int r = 0; r < 4; ++r) o[r] = f2b(ac2[r]);
        *(u16x4*)&logits[fr * LSTR + t * 16 + fq * 4] = *(u16x4*)o;

        cur = nxt;
    }
    __syncthreads();

    // ---- wave-autonomous softmax: wave handles heads {wave, wave+8} ----
    const long long sbase = (long long)b * 16 * 1048576 + (long long)i * 1024;
    const int we = ((i >> 7) + 1) << 7;
    for (int hh = wave; hh < 16; hh += 8) {
        float vals[16];
        float mx = -3.0e38f;
        #pragma unroll
        for (int s = 0; s < 4; ++s) {
            if (s > slast) continue;                 // uniform branch
            u16x4 r4 = *(const u16x4*)&logits[hh * LSTR + lane * 4 + 256 * s];
            if (s < slast) {
                #pragma unroll
                for (int e = 0; e < 4; ++e) {
                    float v = b2f(r4[e]);
                    vals[s * 4 + e] = v;
                    mx = fmaxf(mx, v);
                }
            } else {
                #pragma unroll
                for (int e = 0; e < 4; ++e) {
                    int j = lane * 4 + 256 * s + e;
                    float v = (j <= i) ? b2f(r4[e]) : -3.0e38f;
                    vals[s * 4 + e] = v;
                    mx = fmaxf(mx, v);
                }
            }
        }
        #pragma unroll
        for (int off = 1; off < 64; off <<= 1)
            mx = fmaxf(mx, __shfl_xor(mx, off));
        float sm = 0.f;
        #pragma unroll
        for (int s = 0; s < 4; ++s) {
            if (s > slast) continue;                 // uniform branch
            if (s < slast) {
                #pragma unroll
                for (int e = 0; e < 4; ++e) {
                    float ev = __expf(vals[s * 4 + e] - mx);
                    vals[s * 4 + e] = ev;
                    sm += ev;
                }
            } else {
                #pragma unroll
                for (int e = 0; e < 4; ++e) {
                    float ev = (vals[s * 4 + e] > -1.0e37f)
                                   ? __expf(vals[s * 4 + e] - mx) : 0.f;
                    vals[s * 4 + e] = ev;
                    sm += ev;
                }
            }
        }
        #pragma unroll
        for (int off = 1; off < 64; off <<= 1)
            sm += __shfl_xor(sm, off);
        const float inv = __builtin_amdgcn_rcpf(sm);
        const long long hb = sbase + (long long)hh * 1048576;
        #pragma unroll
        for (int s = 0; s < 4; ++s) {
            if (s > slast) continue;                 // uniform branch
            int j0v = lane * 4 + 256 * s;
            if (s < slast || j0v < we) {
                u16 o[4];
                #pragma unroll
                for (int e = 0; e < 4; ++e) o[e] = f2b(vals[s * 4 + e] * inv);
                *(u16x4*)&W[hb + j0v] = *(u16x4*)o;
            }
        }
    }
}

// ---------------------------------------------------------------------------
extern "C" void kernel_launch(void* const* d_in, const int* in_sizes, int n_in,
                              void* d_out, int out_size, void* d_ws, size_t ws_size,
                              hipStream_t stream)
{
    const float* x     = (const float*)d_in[0];
    const float* w_qkv = (const float*)d_in[1];
    const float* w_o   = (const float*)d_in[2];
    const float* log_p = (const float*)d_in[3];
    const float* log_a = (const float*)d_in[4];
    const float* w1    = (const float*)d_in[5];
    const float* b1    = (const float*)d_in[6];
    const float* w2    = (const float*)d_in[7];
    const float* b2    = (const float*)d_in[8];
    float* out = (float*)d_out;

    char* p = (char*)d_ws;
    u16* x_bf    = (u16*)p;    p += 2097152ll * 2;
    u16* wqkvT   = (u16*)p;    p += 3145728ll * 2;   // (3HD, HID)
    u16* woT     = (u16*)p;    p += 1048576ll * 2;   // (HID, HD)
    u16* q_bf    = (u16*)p;    p += 2097152ll * 2;   // (B,H,L,D)
    u16* k_bf    = (u16*)p;    p += 2097152ll * 2;
    u16* vT      = (u16*)p;    p += 2097152ll * 2;   // (B,H,D,L)
    u16* scoresW = (u16*)p;    p += 33554432ll * 2;  // W: (B,H,L,L) post-softmax
    u16* St      = (u16*)p;    p += 33554432ll * 2;  // St: (B,L,L,H) raw scores
    u16* attn_bf = (u16*)p;    p += 2097152ll * 2;   // (B,L,H*D)
    u16* ktab    = (u16*)p;    p += 16384ll * 2;     // kerple[dist][h]
    float* ctab  = (float*)p;  p += 65536ll * 4;     // cos[l][d]
    float* stab  = (float*)p;  p += 65536ll * 4;     // signed sin[l][d]

    // 0. fused prep: cast x (vectorized), transpose weights, kerple + rope
    prep<<<2624, 256, 0, stream>>>(x, x_bf, w_qkv, wqkvT, w_o, woT,
                                   log_p, log_a, ktab, ctab, stab);

    // 0b. ATTRIBUTION (round 19): prep is idempotent (pure function of
    // inputs). Second launch leaves all workspace buffers bit-identical.
    prep<<<2624, 256, 0, stream>>>(x, x_bf, w_qkv, wqkvT, w_o, woT,
                                   log_p, log_a, ktab, ctab, stab);

    // 1. qkv projection + fused RoPE/split/V-transpose (measured 22.1 us)
    qkv_rope<<<dim3(24, 32), 256, 0, stream>>>(
        x_bf, wqkvT, ctab, stab, q_bf, k_bf, vT);

    // 2. St = (q @ k^T)/8 for all heads, stored (b,i,j,h), LDS-staged store
    qk_allh<<<dim3(16, 32, 2), 256, 0, stream>>>(q_bf, k_bf, St);

    // 3. FUSED kerple + DAPE MLP + softmax: St -> W (measured 30.5 us)
    dape_soft<<<dim3(1024, 2), 512, 0, stream>>>(
        St, scoresW, ktab, w1, b1, w2, b2);

    // 4. attn_bf = W @ v, triangular K, gl2lds16-staged GEMM structure
    pv_direct<<<dim3(16, 32), 256, 0, stream>>>(scoresW, vT, attn_bf);

    // 5. out = attn_fl @ w_o, staged epilogue (BK=64, T2 swizzle)
    gemm_bt<64, 64, 32, 32, false><<<dim3(16, 32, 1), 256, 0, stream>>>(
        attn_bf, woT, out, 2048, 1024, 1024, 1.0f);

    // 5b. ATTRIBUTION (round 19): gemm_bt is idempotent (reads attn_bf/woT,
    // deterministically rewrites out). Delta_total = t_prep + t_gemm.
    gemm_bt<64, 64, 32, 32, false><<<dim3(16, 32, 1), 256, 0, stream>>>(
        attn_bf, woT, out, 2048, 1024, 1024, 1.0f);
}

// Round 20
// 184.336 us; speedup vs baseline: 1.1312x; 1.1096x over previous
//
#include <hip/hip_runtime.h>
#include <math.h>

#define Bv 2
#define Lv 1024
#define Hv 16
#define Dv 64
#define HIDv 1024

typedef unsigned short u16;
typedef short bf16x8 __attribute__((ext_vector_type(8)));
typedef unsigned short u16x4 __attribute__((ext_vector_type(4)));
typedef float f32x4 __attribute__((ext_vector_type(4)));

// round-half-up bf16 (2 inst; exact .5-ulp ties are measure-zero)
__device__ __forceinline__ u16 f2b(float f) {
    union { float f; unsigned u; } v; v.f = f;
    return (u16)((v.u + 0x8000u) >> 16);
}
__device__ __forceinline__ float b2f(u16 h) {
    union { unsigned u; float f; } v; v.u = ((unsigned)h) << 16;
    return v.f;
}

// async global->LDS, 16B per lane (wave-uniform base + lane*16 order).
__device__ __forceinline__ void gl2lds16(const u16* g, u16* l) {
    __builtin_amdgcn_global_load_lds(
        (const __attribute__((address_space(1))) unsigned int*)g,
        (__attribute__((address_space(3))) unsigned int*)l,
        16, 0, 0);
}

// tanh-form gelu: x * sigmoid(1.5957691*(x + 0.044715*x^3)); max err ~1e-3.
__device__ __forceinline__ float gelu_fast(float x) {
    float x2 = x * x;
    float inner = __builtin_fmaf(0.044715f * x2, x, x);
    float e = __expf(-1.5957691216057308f * inner);
    return x * __builtin_amdgcn_rcpf(1.0f + e);
}

// ---------------------------------------------------------------------------
// QKV projection with fused RoPE + split + V-transpose.
// BK=64 (16 MFMA per barrier-pair) with T2 XOR-swizzle (source + read).
// MEASURED 22.1 us (round-18 double-launch).
// LDS: As 8K + Bs 16K = 24 KB; Ct (17.4 KB) overlays. grid 24x32 = 768.
// ---------------------------------------------------------------------------
__global__ __launch_bounds__(256) void qkv_rope(
    const u16* __restrict__ A, const u16* __restrict__ B,
    const float* __restrict__ ctab, const float* __restrict__ stab,
    u16* __restrict__ q, u16* __restrict__ k, u16* __restrict__ vT)
{
    __shared__ __align__(16) char pool[24576];   // As 8KB + Bs 16KB; Ct overlay
    u16* As = (u16*)pool;                 // 64*64  u16 (8 KB), swizzled
    u16* Bs = (u16*)(pool + 8192);        // 128*64 u16 (16 KB), swizzled
    u16* Ct = (u16*)pool;                 // 64*136 u16 (epilogue only)

    const int m0 = blockIdx.y * 64;
    const int n0 = blockIdx.x * 128;
    const int K = 1024;

    const int tid = threadIdx.x;
    const int lane = tid & 63;
    const int wave = tid >> 6;
    const int wm0 = (wave >> 1) * 32;
    const int wn0 = (wave & 1) * 64;
    const int fr = lane & 15;
    const int fq = lane >> 4;

    f32x4 acc[2][4];
    #pragma unroll
    for (int i = 0; i < 2; ++i)
        #pragma unroll
        for (int j = 0; j < 4; ++j) acc[i][j] = (f32x4){0.f, 0.f, 0.f, 0.f};

    for (int k0 = 0; k0 < K; k0 += 64) {
        #pragma unroll
        for (int it = 0; it < 2; ++it) {     // A: 64 rows x 64 cols, swz source
            int cid = tid + it * 256;
            int r = cid >> 3, ch = cid & 7;
            gl2lds16(A + (long long)(m0 + r) * K + k0 + (ch ^ (r & 7)) * 8,
                     &As[cid * 8]);
        }
        #pragma unroll
        for (int it = 0; it < 4; ++it) {     // B: 128 rows x 64 cols, swz source
            int cid = tid + it * 256;
            int r = cid >> 3, ch = cid & 7;
            gl2lds16(B + (long long)(n0 + r) * K + k0 + (ch ^ (r & 7)) * 8,
                     &Bs[cid * 8]);
        }
        __syncthreads();
        bf16x8 af[2][2], bfr[4][2];
        #pragma unroll
        for (int i = 0; i < 2; ++i) {
            int row = wm0 + i * 16 + fr;
            #pragma unroll
            for (int p = 0; p < 2; ++p)
                af[i][p] = *(const bf16x8*)
                    &As[row * 64 + ((p * 32 + fq * 8) ^ ((row & 7) << 3))];
        }
        #pragma unroll
        for (int j = 0; j < 4; ++j) {
            int row = wn0 + j * 16 + fr;
            #pragma unroll
            for (int p = 0; p < 2; ++p)
                bfr[j][p] = *(const bf16x8*)
                    &Bs[row * 64 + ((p * 32 + fq * 8) ^ ((row & 7) << 3))];
        }
        #pragma unroll
        for (int p = 0; p < 2; ++p)
            #pragma unroll
            for (int i = 0; i < 2; ++i)
                #pragma unroll
                for (int j = 0; j < 4; ++j)
                    acc[i][j] = __builtin_amdgcn_mfma_f32_16x16x32_bf16(
                        af[i][p], bfr[j][p], acc[i][j], 0, 0, 0);
        __syncthreads();
    }

    const int b = m0 >> 10;                   // tile never crosses batch

    if (n0 >= 2048) {
        // ---- V: store transposed directly (4 consecutive l per lane) ----
        #pragma unroll
        for (int i = 0; i < 2; ++i)
            #pragma unroll
            for (int j = 0; j < 4; ++j) {
                int vcol = (n0 - 2048) + wn0 + j * 16 + fr;
                int head = vcol >> 6, d = vcol & 63;
                int l = ((m0 + wm0 + i * 16 + fq * 4) & 1023);
                u16 o[4];
                #pragma unroll
                for (int r = 0; r < 4; ++r) o[r] = f2b(acc[i][j][r]);
                *(u16x4*)&vT[((long long)(b * 16 + head) * 64 + d) * 1024 + l] =
                    *(u16x4*)o;
            }
        return;
    }

    // ---- Q/K: stage in LDS (overlaying As/Bs), RoPE on readback ----
    #pragma unroll
    for (int i = 0; i < 2; ++i)
        #pragma unroll
        for (int j = 0; j < 4; ++j)
            #pragma unroll
            for (int r = 0; r < 4; ++r)
                Ct[(wm0 + i * 16 + fq * 4 + r) * 136 + wn0 + j * 16 + fr] =
                    f2b(acc[i][j][r]);
    __syncthreads();

    u16* dst = (n0 >= 1024) ? k : q;
    const int nh = n0 & 1023;
    #pragma unroll
    for (int c = 0; c < 4; ++c) {
        int cid = tid + c * 256;
        int row = cid >> 4, kc = cid & 15;
        int l = (m0 + row) & 1023;
        int head = (nh >> 6) + (kc >> 3);
        int d0 = (kc & 7) * 8;
        bf16x8 x  = *(const bf16x8*)&Ct[row * 136 + kc * 8];
        bf16x8 xp = *(const bf16x8*)&Ct[row * 136 + (kc ^ 4) * 8];
        float4 c0 = *(const float4*)&ctab[l * 64 + d0];
        float4 c1 = *(const float4*)&ctab[l * 64 + d0 + 4];
        float4 s0 = *(const float4*)&stab[l * 64 + d0];
        float4 s1 = *(const float4*)&stab[l * 64 + d0 + 4];
        float ct[8] = {c0.x, c0.y, c0.z, c0.w, c1.x, c1.y, c1.z, c1.w};
        float st[8] = {s0.x, s0.y, s0.z, s0.w, s1.x, s1.y, s1.z, s1.w};
        u16 o[8];
        #pragma unroll
        for (int e = 0; e < 8; ++e)
            o[e] = f2b(b2f((u16)x[e]) * ct[e] + b2f((u16)xp[e]) * st[e]);
        *(bf16x8*)&dst[((long long)(b * 16 + head) * 1024 + l) * 64 + d0] =
            *(bf16x8*)o;
    }
}

// ---------------------------------------------------------------------------
// bf16 MFMA GEMM: C = alpha * A @ B^T. BK=64 + T2 XOR-swizzle.
// (With prep: measured 18.1 us combined, round-19 double-launch.)
// ---------------------------------------------------------------------------
template<int BM, int BN, int WM, int WN, bool CBF16>
__global__ __launch_bounds__(256) void gemm_bt(
    const u16* __restrict__ A, const u16* __restrict__ B, void* __restrict__ Cv,
    int M, int N, int K, float alpha)
{
    constexpr int NW = BN / WN;
    constexpr int MI = WM / 16;
    constexpr int NI = WN / 16;
    constexpr int LDB = BN + 8;
    constexpr int LDF = BN + 4;
    __shared__ u16 As[BM * 64];
    __shared__ u16 Bs[BN * 64];
    __shared__ u16 Ctb[CBF16 ? BM * LDB : 1];
    __shared__ float Ctf[CBF16 ? 1 : BM * LDF];

    const int m0 = blockIdx.y * BM;
    const int n0 = blockIdx.x * BN;

    const int tid = threadIdx.x;
    const int lane = tid & 63;
    const int wave = tid >> 6;
    const int wm0 = (wave / NW) * WM;
    const int wn0 = (wave % NW) * WN;
    const int fr = lane & 15;
    const int fq = lane >> 4;

    f32x4 acc[MI][NI];
    #pragma unroll
    for (int i = 0; i < MI; ++i)
        #pragma unroll
        for (int j = 0; j < NI; ++j) acc[i][j] = (f32x4){0.f, 0.f, 0.f, 0.f};

    for (int k0 = 0; k0 < K; k0 += 64) {
        #pragma unroll
        for (int it = 0; it < BM / 32; ++it) {   // BM rows x 8 chunks
            int cid = tid + it * 256;
            int r = cid >> 3, ch = cid & 7;
            gl2lds16(A + (long long)(m0 + r) * K + k0 + (ch ^ (r & 7)) * 8,
                     &As[cid * 8]);
        }
        #pragma unroll
        for (int it = 0; it < BN / 32; ++it) {
            int cid = tid + it * 256;
            int r = cid >> 3, ch = cid & 7;
            gl2lds16(B + (long long)(n0 + r) * K + k0 + (ch ^ (r & 7)) * 8,
                     &Bs[cid * 8]);
        }
        __syncthreads();
        bf16x8 af[MI][2], bfr[NI][2];
        #pragma unroll
        for (int i = 0; i < MI; ++i) {
            int row = wm0 + i * 16 + fr;
            #pragma unroll
            for (int p = 0; p < 2; ++p)
                af[i][p] = *(const bf16x8*)
                    &As[row * 64 + ((p * 32 + fq * 8) ^ ((row & 7) << 3))];
        }
        #pragma unroll
        for (int j = 0; j < NI; ++j) {
            int row = wn0 + j * 16 + fr;
            #pragma unroll
            for (int p = 0; p < 2; ++p)
                bfr[j][p] = *(const bf16x8*)
                    &Bs[row * 64 + ((p * 32 + fq * 8) ^ ((row & 7) << 3))];
        }
        #pragma unroll
        for (int p = 0; p < 2; ++p)
            #pragma unroll
            for (int i = 0; i < MI; ++i)
                #pragma unroll
                for (int j = 0; j < NI; ++j)
                    acc[i][j] = __builtin_amdgcn_mfma_f32_16x16x32_bf16(
                        af[i][p], bfr[j][p], acc[i][j], 0, 0, 0);
        __syncthreads();
    }

    #pragma unroll
    for (int i = 0; i < MI; ++i)
        #pragma unroll
        for (int j = 0; j < NI; ++j)
            #pragma unroll
            for (int r = 0; r < 4; ++r) {
                int row = wm0 + i * 16 + fq * 4 + r;
                int col = wn0 + j * 16 + fr;
                float v = acc[i][j][r] * alpha;
                if (CBF16) Ctb[row * LDB + col] = f2b(v);
                else       Ctf[row * LDF + col] = v;
            }
    __syncthreads();
    if (CBF16) {
        constexpr int CPR = BN / 8;
        #pragma unroll
        for (int c = 0; c < (BM * BN) / (8 * 256); ++c) {
            int cid = tid + c * 256;
            int row = cid / CPR, kc = cid % CPR;
            *(bf16x8*)((u16*)Cv + (long long)(m0 + row) * N + n0 + kc * 8) =
                *(const bf16x8*)&Ctb[row * LDB + kc * 8];
        }
    } else {
        constexpr int CPR = BN / 4;
        #pragma unroll
        for (int c = 0; c < (BM * BN) / (4 * 256); ++c) {
            int cid = tid + c * 256;
            int row = cid / CPR, kc = cid % CPR;
            *(float4*)((float*)Cv + (long long)(m0 + row) * N + n0 + kc * 4) =
                *(const float4*)&Ctf[row * LDF + kc * 4];
        }
    }
}

// ---------------------------------------------------------------------------
// QK^T, all 16 heads per block, scores stored TRANSPOSED: St(b, i, j, h).
// ROUND-20: head loop fully unrolled -- the per-head body is {12 direct
// global fragment loads -> 16 MFMA -> 32 LDS scatter} with no barriers
// between heads; unrolling lets the compiler hoist head hh+1's global
// loads (independent address space from the LDS scatter) under head hh's
// MFMA+scatter, hiding the ~900-cycle load latency (same mechanism as
// dape's cur/nxt prefetch; pv_direct's round-17 fix). Same ops, same
// per-head order -> bit-identical output.
// 32i x 64j, 64 KB Ts, 2 blocks/CU; XOR-swizzled scatter (8-way), ONE
// barrier, coalesced b128 readback. grid (16, 32, B).
// ---------------------------------------------------------------------------
__global__ __launch_bounds__(256) void qk_allh(
    const u16* __restrict__ Q, const u16* __restrict__ K, u16* __restrict__ St)
{
    const int n0 = blockIdx.x * 64;          // j
    const int m0 = blockIdx.y * 32;          // i
    if (n0 > m0 + 31) return;                // fully above diagonal
    const int b = blockIdx.z;

    __shared__ __align__(16) u16 Ts[32 * 64 * 16];   // 65536 B

    const int tid = threadIdx.x;
    const int lane = tid & 63;
    const int wave = tid >> 6;
    const int fr = lane & 15;
    const int fq = lane >> 4;

    const long long qkbase = (long long)b * 16 * 65536;   // (b,h,l,d)
    u16* Sb = St + (long long)b * 1024 * 1024 * 16;       // (b,i,j,h)

    #pragma unroll
    for (int hh = 0; hh < 4; ++hh) {
        const int h = wave * 4 + hh;
        const u16* A  = Q + qkbase + (long long)h * 65536;
        const u16* Bp = K + qkbase + (long long)h * 65536;

        bf16x8 af[2][2], bf[4][2];
        #pragma unroll
        for (int p = 0; p < 2; ++p) {
            #pragma unroll
            for (int ii = 0; ii < 2; ++ii)
                af[ii][p] = *(const bf16x8*)&A[(m0 + ii * 16 + fr) * 64 + p * 32 + fq * 8];
            #pragma unroll
            for (int j = 0; j < 4; ++j)
                bf[j][p]  = *(const bf16x8*)&Bp[(n0 + j * 16 + fr) * 64 + p * 32 + fq * 8];
        }

        f32x4 acc[2][4];
        #pragma unroll
        for (int ii = 0; ii < 2; ++ii)
            #pragma unroll
            for (int j = 0; j < 4; ++j) acc[ii][j] = (f32x4){0.f, 0.f, 0.f, 0.f};

        #pragma unroll
        for (int p = 0; p < 2; ++p)
            #pragma unroll
            for (int ii = 0; ii < 2; ++ii)
                #pragma unroll
                for (int j = 0; j < 4; ++j)
                    acc[ii][j] = __builtin_amdgcn_mfma_f32_16x16x32_bf16(
                        af[ii][p], bf[j][p], acc[ii][j], 0, 0, 0);

        // scatter this head's 32x64 tile into LDS (i, j, h), swizzled
        #pragma unroll
        for (int ii = 0; ii < 2; ++ii)
            #pragma unroll
            for (int j = 0; j < 4; ++j) {
                const int jc = j * 16 + fr;
                #pragma unroll
                for (int r = 0; r < 4; ++r) {
                    const int ir = ii * 16 + fq * 4 + r;
                    int byte = ((ir * 64 + jc) * 16 + h) * 2;
                    byte ^= (((jc + (ir >> 2)) & 1) << 4);
                    *(u16*)&((char*)Ts)[byte] = f2b(acc[ii][j][r] * 0.125f);
                }
            }
    }
    __syncthreads();

    // coalesced readback: 16 iters x 256 threads x 16B
    const long long gb = (long long)m0 * 16384 + n0 * 16;
    #pragma unroll
    for (int c = 0; c < 16; ++c) {
        int o = (c * 256 + tid) * 8;                   // elem offset in tile
        int p = ((o >> 4) + (o >> 12)) & 1;            // (jc + (ir>>2)) & 1
        int ldsb = (o * 2) ^ (p << 4);
        bf16x8 v = *(const bf16x8*)&((const char*)Ts)[ldsb];
        *(bf16x8*)&Sb[gb + (long long)(o >> 10) * 16384 + (o & 1023)] = v;
    }
}

// ---------------------------------------------------------------------------
// PV: attn_bf = W @ V^T (triangular K), gl2lds16-staged GEMM (verified
// round 17: direct -> staged, total -15.9us). 256 thr, 4 waves of 32x32;
// T2 source+read swizzle. LDS 25 KB -> 6 blocks/CU.
// grid (16, B*H); writes bf16 into (B,L,H*D).
// ---------------------------------------------------------------------------
__global__ __launch_bounds__(256) void pv_direct(
    const u16* __restrict__ W, const u16* __restrict__ VT, u16* __restrict__ O)
{
    const int m0 = blockIdx.x * 64;
    const int bh = blockIdx.y;
    const u16* A = W + (long long)bh * 1048576;    // (L,L), row stride 1024
    const u16* B = VT + (long long)bh * 65536;     // (D=64,L), row stride 1024
    const int b = bh >> 4, h = bh & 15;

    __shared__ u16 As[64 * 64];    // 8 KB, swizzled W-tile
    __shared__ u16 Bs[64 * 64];    // 8 KB, swizzled V-tile
    __shared__ u16 Ct[64 * 72];    // 9 KB epilogue

    const int tid = threadIdx.x;
    const int lane = tid & 63;
    const int wave = tid >> 6;
    const int wm0 = (wave >> 1) * 32;
    const int wn0 = (wave & 1) * 32;
    const int fr = lane & 15;
    const int fq = lane >> 4;

    f32x4 acc[2][2];
    #pragma unroll
    for (int i = 0; i < 2; ++i)
        #pragma unroll
        for (int j = 0; j < 2; ++j) acc[i][j] = (f32x4){0.f, 0.f, 0.f, 0.f};

    const int Kend = m0 + 64;
    for (int k0 = 0; k0 < Kend; k0 += 64) {
        #pragma unroll
        for (int it = 0; it < 2; ++it) {     // A: 64 rows x 64 cols, swz source
            int cid = tid + it * 256;
            int r = cid >> 3, ch = cid & 7;
            gl2lds16(A + (long long)(m0 + r) * 1024 + k0 + (ch ^ (r & 7)) * 8,
                     &As[cid * 8]);
        }
        #pragma unroll
        for (int it = 0; it < 2; ++it) {     // B: 64 d-rows x 64 l-cols
            int cid = tid + it * 256;
            int r = cid >> 3, ch = cid & 7;
            gl2lds16(B + (long long)r * 1024 + k0 + (ch ^ (r & 7)) * 8,
                     &Bs[cid * 8]);
        }
        __syncthreads();
        bf16x8 af[2][2], bfr[2][2];
        #pragma unroll
        for (int i = 0; i < 2; ++i) {
            int row = wm0 + i * 16 + fr;
            #pragma unroll
            for (int p = 0; p < 2; ++p)
                af[i][p] = *(const bf16x8*)
                    &As[row * 64 + ((p * 32 + fq * 8) ^ ((row & 7) << 3))];
        }
        #pragma unroll
        for (int j = 0; j < 2; ++j) {
            int row = wn0 + j * 16 + fr;
            #pragma unroll
            for (int p = 0; p < 2; ++p)
                bfr[j][p] = *(const bf16x8*)
                    &Bs[row * 64 + ((p * 32 + fq * 8) ^ ((row & 7) << 3))];
        }
        #pragma unroll
        for (int p = 0; p < 2; ++p)
            #pragma unroll
            for (int i = 0; i < 2; ++i)
                #pragma unroll
                for (int j = 0; j < 2; ++j)
                    acc[i][j] = __builtin_amdgcn_mfma_f32_16x16x32_bf16(
                        af[i][p], bfr[j][p], acc[i][j], 0, 0, 0);
        __syncthreads();
    }

    #pragma unroll
    for (int i = 0; i < 2; ++i)
        #pragma unroll
        for (int j = 0; j < 2; ++j)
            #pragma unroll
            for (int r = 0; r < 4; ++r)
                Ct[(wm0 + i * 16 + fq * 4 + r) * 72 + wn0 + j * 16 + fr] =
                    f2b(acc[i][j][r]);
    __syncthreads();
    const long long ob = (long long)b * 1048576 + h * 64;
    #pragma unroll
    for (int c = 0; c < 2; ++c) {
        int cid = tid + c * 256;
        int row = cid >> 3, kc = cid & 7;
        *(bf16x8*)&O[ob + (long long)(m0 + row) * 1024 + kc * 8] =
            *(const bf16x8*)&Ct[row * 72 + kc * 8];
    }
}

// ---------------------------------------------------------------------------
// Fused prep: vectorized cast x (blocks 0..1023, 8 elems/thread),
// transpose wqkv (1024..1791, 768 blocks), transpose wo (1792..2047, 256
// blocks), kerple (2048..2111), rope (2112..2623). Total grid: 2624.
// ---------------------------------------------------------------------------
__global__ __launch_bounds__(256) void prep(
    const float* __restrict__ x, u16* __restrict__ x_bf,
    const float* __restrict__ w_qkv, u16* __restrict__ wqkvT,
    const float* __restrict__ w_o, u16* __restrict__ woT,
    const float* __restrict__ log_p, const float* __restrict__ log_a,
    u16* __restrict__ ktab, float* __restrict__ ctab, float* __restrict__ stab)
{
    __shared__ float tile[64][65];
    const int bid = blockIdx.x;
    const int tid = threadIdx.x;

    if (bid < 1024) {                          // x cast: 8 elems/thread
        int i8 = (bid * 256 + tid) * 8;
        float4 v0 = *(const float4*)&x[i8];
        float4 v1 = *(const float4*)&x[i8 + 4];
        u16 o[8];
        o[0] = f2b(v0.x); o[1] = f2b(v0.y); o[2] = f2b(v0.z); o[3] = f2b(v0.w);
        o[4] = f2b(v1.x); o[5] = f2b(v1.y); o[6] = f2b(v1.z); o[7] = f2b(v1.w);
        *(bf16x8*)&x_bf[i8] = *(bf16x8*)o;
        return;
    }
    if (bid >= 2112) {
        int idx = (bid - 2112) * 256 + tid;    // 0..131071: both rope tables
        int e = idx & 65535;
        int l = e >> 6, d = e & 63;
        float inv_freq = __expf((float)(d & 31) * -0.28782313662425574f);
        float arg = (float)l * inv_freq;
        if (idx < 65536) ctab[e] = __cosf(arg);
        else             stab[e] = (d < 32) ? -__sinf(arg) : __sinf(arg);
        return;
    }
    if (bid >= 2048) {
        int idx = (bid - 2048) * 256 + tid;    // 16384
        int h = idx & 15, dist = idx >> 4;
        float pp = log1pf(__expf(log_p[h]));
        float aa = log1pf(__expf(log_a[h]));
        ktab[idx] = f2b(-pp * log1pf(aa * (float)dist));
        return;
    }
    const float* src; u16* dst; int M, N, bx, by;
    if (bid < 1792) { int t = bid - 1024; bx = t % 48; by = t / 48; src = w_qkv; dst = wqkvT; M = 1024; N = 3072; }
    else            { int t = bid - 1792; bx = t % 16; by = t / 16; src = w_o;   dst = woT;   M = 1024; N = 1024; }
    const int m0 = by * 64, n0 = bx * 64;
    #pragma unroll
    for (int c = 0; c < 4; ++c) {
        int f = tid + c * 256;
        int r = f >> 4, cs = (f & 15) * 4;
        float4 v = *(const float4*)&src[(long long)(m0 + r) * N + n0 + cs];
        tile[r][cs] = v.x; tile[r][cs + 1] = v.y;
        tile[r][cs + 2] = v.z; tile[r][cs + 3] = v.w;
    }
    __syncthreads();
    int nl = tid >> 2, ms = (tid & 3) * 16;
    u16 outv[16];
    #pragma unroll
    for (int c = 0; c < 16; ++c) outv[c] = f2b(tile[ms + c][nl]);
    *(bf16x8*)&dst[(long long)(n0 + nl) * M + m0 + ms]     = *(bf16x8*)&outv[0];
    *(bf16x8*)&dst[(long long)(n0 + nl) * M + m0 + ms + 8] = *(bf16x8*)&outv[8];
}

// ---------------------------------------------------------------------------
// FUSED kerple + DAPE MLP (MFMA) + causal softmax. (MEASURED 30.5 us.)
// Reads St(b,i,j,h) DIRECTLY as MFMA fragments: lanes fq<2 read 16 head
// scores, fq>=2 read kerple; one-deep prefetch; one barrier before softmax.
// Softmax writes W(b,h,i,j) for pv_direct.
// LDS: logits 33.4 KB + per-wave hid 9.2 KB = 42.6 KB -> 3 blocks/CU.
// ---------------------------------------------------------------------------
#define LSTR 1044

__global__ __launch_bounds__(512) void dape_soft(
    const u16* __restrict__ St, u16* __restrict__ W,
    const u16* __restrict__ ktab,
    const float* __restrict__ w1, const float* __restrict__ b1,
    const float* __restrict__ w2, const float* __restrict__ b2)
{
    const int i = 1023 - blockIdx.x;
    const int b = blockIdx.y;

    __shared__ u16 logits[16 * LSTR];        // 33.4 KB
    __shared__ u16 hid[8][16 * 36];          // 9.2 KB (per-wave transpose)

    const int tid = threadIdx.x;
    const int lane = tid & 63;
    const int wave = tid >> 6;
    const int fr = lane & 15;
    const int fq = lane >> 4;

    bf16x8 B1a, B1b, B2f, Bid;
    #pragma unroll
    for (int e = 0; e < 8; ++e) {
        int c = fq * 8 + e;
        B1a[e] = (short)f2b(w1[c * 32 + fr]);
        B1b[e] = (short)f2b(w1[c * 32 + 16 + fr]);
        B2f[e] = (short)f2b(w2[c * 16 + fr]);
        Bid[e] = (short)((c == fr || c == 16 + fr) ? 0x3F80 : 0);
    }
    const float b1a = b1[fr], b1b = b1[16 + fr], b2v = b2[fr];

    const long long sti = ((long long)b * 1024 + i) * 1024;  // St row base (x16)
    const int ntile = (i >> 4) + 1;          // 16-j tiles with jt <= i
    const int slast = i >> 8;                // last live 256-segment
    u16* hidp = &hid[wave][0];

    // ---- MLP phase: per-wave autonomous, direct global fragment loads ----
    bf16x8 cur;
    {
        int t0 = (wave < ntile) ? wave : 0;
        int j = t0 * 16 + fr;
        int dist = i - j; if (dist < 0) dist = 0;
        const u16* pp = (fq < 2) ? &St[(sti + j) * 16 + fq * 8]
                                 : &ktab[dist * 16 + (fq - 2) * 8];
        cur = *(const bf16x8*)pp;
    }
    for (int t = wave; t < ntile; t += 8) {
        bf16x8 nxt = cur;
        if (t + 8 < ntile) {
            int j = (t + 8) * 16 + fr;
            int dist = i - j; if (dist < 0) dist = 0;
            const u16* pp = (fq < 2) ? &St[(sti + j) * 16 + fq * 8]
                                     : &ktab[dist * 16 + (fq - 2) * 8];
            nxt = *(const bf16x8*)pp;
        }

        f32x4 z = (f32x4){0.f, 0.f, 0.f, 0.f};
        f32x4 ac1a = __builtin_amdgcn_mfma_f32_16x16x32_bf16(cur, B1a, z, 0, 0, 0);
        f32x4 ac1b = __builtin_amdgcn_mfma_f32_16x16x32_bf16(cur, B1b, z, 0, 0, 0);
        f32x4 cres = __builtin_amdgcn_mfma_f32_16x16x32_bf16(
            cur, Bid, (f32x4){b2v, b2v, b2v, b2v}, 0, 0, 0);

        #pragma unroll
        for (int r = 0; r < 4; ++r) {
            float g0 = gelu_fast(ac1a[r] + b1a);
            float g1 = gelu_fast(ac1b[r] + b1b);
            hidp[(fq * 4 + r) * 36 + fr]      = f2b(g0);
            hidp[(fq * 4 + r) * 36 + 16 + fr] = f2b(g1);
        }
        bf16x8 A2 = *(const bf16x8*)&hidp[fr * 36 + fq * 8];
        f32x4 ac2 = __builtin_amdgcn_mfma_f32_16x16x32_bf16(A2, B2f, cres, 0, 0, 0);

        u16 o[4];
        #pragma unroll
        for (int r = 0; r < 4; ++r) o[r] = f2b(ac2[r]);
        *(u16x4*)&logits[fr * LSTR + t * 16 + fq * 4] = *(u16x4*)o;

        cur = nxt;
    }
    __syncthreads();

    // ---- wave-autonomous softmax: wave handles heads {wave, wave+8} ----
    const long long sbase = (long long)b * 16 * 1048576 + (long long)i * 1024;
    const int we = ((i >> 7) + 1) << 7;
    for (int hh = wave; hh < 16; hh += 8) {
        float vals[16];
        float mx = -3.0e38f;
        #pragma unroll
        for (int s = 0; s < 4; ++s) {
            if (s > slast) continue;                 // uniform branch
            u16x4 r4 = *(const u16x4*)&logits[hh * LSTR + lane * 4 + 256 * s];
            if (s < slast) {
                #pragma unroll
                for (int e = 0; e < 4; ++e) {
                    float v = b2f(r4[e]);
                    vals[s * 4 + e] = v;
                    mx = fmaxf(mx, v);
                }
            } else {
                #pragma unroll
                for (int e = 0; e < 4; ++e) {
                    int j = lane * 4 + 256 * s + e;
                    float v = (j <= i) ? b2f(r4[e]) : -3.0e38f;
                    vals[s * 4 + e] = v;
                    mx = fmaxf(mx, v);
                }
            }
        }
        #pragma unroll
        for (int off = 1; off < 64; off <<= 1)
            mx = fmaxf(mx, __shfl_xor(mx, off));
        float sm = 0.f;
        #pragma unroll
        for (int s = 0; s < 4; ++s) {
            if (s > slast) continue;                 // uniform branch
            if (s < slast) {
                #pragma unroll
                for (int e = 0; e < 4; ++e) {
                    float ev = __expf(vals[s * 4 + e] - mx);
                    vals[s * 4 + e] = ev;
                    sm += ev;
                }
            } else {
                #pragma unroll
                for (int e = 0; e < 4; ++e) {
                    float ev = (vals[s * 4 + e] > -1.0e37f)
                                   ? __expf(vals[s * 4 + e] - mx) : 0.f;
                    vals[s * 4 + e] = ev;
                    sm += ev;
                }
            }
        }
        #pragma unroll
        for (int off = 1; off < 64; off <<= 1)
            sm += __shfl_xor(sm, off);
        const float inv = __builtin_amdgcn_rcpf(sm);
        const long long hb = sbase + (long long)hh * 1048576;
        #pragma unroll
        for (int s = 0; s < 4; ++s) {
            if (s > slast) continue;                 // uniform branch
            int j0v = lane * 4 + 256 * s;
            if (s < slast || j0v < we) {
                u16 o[4];
                #pragma unroll
                for (int e = 0; e < 4; ++e) o[e] = f2b(vals[s * 4 + e] * inv);
                *(u16x4*)&W[hb + j0v] = *(u16x4*)o;
            }
        }
    }
}

// ---------------------------------------------------------------------------
extern "C" void kernel_launch(void* const* d_in, const int* in_sizes, int n_in,
                              void* d_out, int out_size, void* d_ws, size_t ws_size,
                              hipStream_t stream)
{
    const float* x     = (const float*)d_in[0];
    const float* w_qkv = (const float*)d_in[1];
    const float* w_o   = (const float*)d_in[2];
    const float* log_p = (const float*)d_in[3];
    const float* log_a = (const float*)d_in[4];
    const float* w1    = (const float*)d_in[5];
    const float* b1    = (const float*)d_in[6];
    const float* w2    = (const float*)d_in[7];
    const float* b2    = (const float*)d_in[8];
    float* out = (float*)d_out;

    char* p = (char*)d_ws;
    u16* x_bf    = (u16*)p;    p += 2097152ll * 2;
    u16* wqkvT   = (u16*)p;    p += 3145728ll * 2;   // (3HD, HID)
    u16* woT     = (u16*)p;    p += 1048576ll * 2;   // (HID, HD)
    u16* q_bf    = (u16*)p;    p += 2097152ll * 2;   // (B,H,L,D)
    u16* k_bf    = (u16*)p;    p += 2097152ll * 2;
    u16* vT      = (u16*)p;    p += 2097152ll * 2;   // (B,H,D,L)
    u16* scoresW = (u16*)p;    p += 33554432ll * 2;  // W: (B,H,L,L) post-softmax
    u16* St      = (u16*)p;    p += 33554432ll * 2;  // St: (B,L,L,H) raw scores
    u16* attn_bf = (u16*)p;    p += 2097152ll * 2;   // (B,L,H*D)
    u16* ktab    = (u16*)p;    p += 16384ll * 2;     // kerple[dist][h]
    float* ctab  = (float*)p;  p += 65536ll * 4;     // cos[l][d]
    float* stab  = (float*)p;  p += 65536ll * 4;     // signed sin[l][d]

    // 0. fused prep: cast x (vectorized), transpose weights, kerple + rope
    prep<<<2624, 256, 0, stream>>>(x, x_bf, w_qkv, wqkvT, w_o, woT,
                                   log_p, log_a, ktab, ctab, stab);

    // 1. qkv projection + fused RoPE/split/V-transpose (measured 22.1 us)
    qkv_rope<<<dim3(24, 32), 256, 0, stream>>>(
        x_bf, wqkvT, ctab, stab, q_bf, k_bf, vT);

    // 2. St = (q @ k^T)/8 for all heads, (b,i,j,h); head loop unrolled
    qk_allh<<<dim3(16, 32, 2), 256, 0, stream>>>(q_bf, k_bf, St);

    // 3. FUSED kerple + DAPE MLP + softmax: St -> W (measured 30.5 us)
    dape_soft<<<dim3(1024, 2), 512, 0, stream>>>(
        St, scoresW, ktab, w1, b1, w2, b2);

    // 4. attn_bf = W @ v, triangular K, gl2lds16-staged GEMM structure
    pv_direct<<<dim3(16, 32), 256, 0, stream>>>(scoresW, vT, attn_bf);

    // 5. out = attn_fl @ w_o, staged epilogue (BK=64, T2 swizzle)
    gemm_bt<64, 64, 32, 32, false><<<dim3(16, 32, 1), 256, 0, stream>>>(
        attn_bf, woT, out, 2048, 1024, 1024, 1.0f);
}